// Round 3
// baseline (493.022 us; speedup 1.0000x reference)
//
#include <hip/hip_runtime.h>
#include <math.h>

#define HD 128   // HEADS*OUT_DIM
#define NH 4     // HEADS

__device__ __forceinline__ float wave_sum(float v) {
    #pragma unroll
    for (int off = 1; off < 64; off <<= 1) v += __shfl_xor(v, off);
    return v;
}

// ---------------- K1: proj = x @ W1 ; alpha_src/alpha_dst per node ----------------
// 64 nodes per block, 256 threads. tid = ng*16 + cg : ng picks 4 nodes, cg picks 8 cols.
__global__ __launch_bounds__(256) void k_proj(
    const float* __restrict__ x, const float* __restrict__ W1,
    const float* __restrict__ a_src, const float* __restrict__ a_dst,
    float* __restrict__ proj, float* __restrict__ asrc, float* __restrict__ adst, int N)
{
    __shared__ float4 xs[64 * 33];   // [64 rows][32 float4 + 1 pad] -> 33.8 KB
    const int tid = threadIdx.x;
    const int node0 = blockIdx.x * 64;

    for (int i = tid; i < 64 * 32; i += 256) {
        int r = i >> 5, c = i & 31;
        float4 v = {0.f, 0.f, 0.f, 0.f};
        int n = node0 + r;
        if (n < N) v = *(const float4*)(x + (size_t)n * HD + c * 4);
        xs[r * 33 + c] = v;
    }
    __syncthreads();

    const int ng = tid >> 4;      // 0..15 (4 nodes each)
    const int cg = tid & 15;      // 0..15 (8 cols each)
    const int c0 = cg * 8;

    float acc[4][8];
    #pragma unroll
    for (int r = 0; r < 4; ++r)
        #pragma unroll
        for (int j = 0; j < 8; ++j) acc[r][j] = 0.f;

    for (int k4 = 0; k4 < 32; ++k4) {
        float4 xv[4];
        #pragma unroll
        for (int r = 0; r < 4; ++r) xv[r] = xs[(ng * 4 + r) * 33 + k4];
        #pragma unroll
        for (int kk = 0; kk < 4; ++kk) {
            const int k = k4 * 4 + kk;
            const float4 w0 = *(const float4*)(W1 + k * HD + c0);
            const float4 w1 = *(const float4*)(W1 + k * HD + c0 + 4);
            #pragma unroll
            for (int r = 0; r < 4; ++r) {
                const float xvk = (kk == 0) ? xv[r].x : (kk == 1) ? xv[r].y : (kk == 2) ? xv[r].z : xv[r].w;
                acc[r][0] += xvk * w0.x; acc[r][1] += xvk * w0.y;
                acc[r][2] += xvk * w0.z; acc[r][3] += xvk * w0.w;
                acc[r][4] += xvk * w1.x; acc[r][5] += xvk * w1.y;
                acc[r][6] += xvk * w1.z; acc[r][7] += xvk * w1.w;
            }
        }
    }

    float as_[8], ad_[8];
    #pragma unroll
    for (int j = 0; j < 8; ++j) { as_[j] = a_src[c0 + j]; ad_[j] = a_dst[c0 + j]; }

    #pragma unroll
    for (int r = 0; r < 4; ++r) {
        const int n = node0 + ng * 4 + r;
        if (n >= N) break;           // uniform across each 4-lane shfl group (same ng)
        float4 o0 = {acc[r][0], acc[r][1], acc[r][2], acc[r][3]};
        float4 o1 = {acc[r][4], acc[r][5], acc[r][6], acc[r][7]};
        *(float4*)(proj + (size_t)n * HD + c0)     = o0;
        *(float4*)(proj + (size_t)n * HD + c0 + 4) = o1;
        float ps = 0.f, pd = 0.f;
        #pragma unroll
        for (int j = 0; j < 8; ++j) { ps += acc[r][j] * as_[j]; pd += acc[r][j] * ad_[j]; }
        ps += __shfl_xor(ps, 1); ps += __shfl_xor(ps, 2);
        pd += __shfl_xor(pd, 1); pd += __shfl_xor(pd, 2);
        if ((cg & 3) == 0) {
            asrc[(size_t)n * NH + (cg >> 2)] = ps;
            adst[(size_t)n * NH + (cg >> 2)] = pd;
        }
    }
}

// ---------------- K2: degree histogram over augmented dst ----------------
// aug edge e: e<E0: (src0[e],dst0[e]); e<2E0: (dst0[j],src0[j]); else self-loop.
__global__ void k_degree(const int* __restrict__ ei, int* __restrict__ deg, int N, int E0_) {
    const int e = blockIdx.x * blockDim.x + threadIdx.x;
    const int ea = 2 * E0_ + N;
    if (e >= ea) return;
    int d;
    if (e < E0_)            d = ei[E0_ + e];      // dst0[e]
    else if (e < 2 * E0_)   d = ei[e - E0_];      // src0[j]
    else                    d = e - 2 * E0_;      // self loop
    atomicAdd(deg + d, 1);
}

// ---------------- K3: exclusive scan deg -> row_start, cursor ----------------
__global__ __launch_bounds__(1024) void k_scan(
    const int* __restrict__ deg, int* __restrict__ row_start, int* __restrict__ cursor, int N)
{
    __shared__ int wsum[16];
    const int tid = threadIdx.x;
    const int chunk = (N + 1023) >> 10;
    const int lo = tid * chunk;
    const int hi = min(lo + chunk, N);
    int s = 0;
    for (int i = lo; i < hi; ++i) s += deg[i];
    const int lane = tid & 63, wid = tid >> 6;
    int incl = s;
    #pragma unroll
    for (int off = 1; off < 64; off <<= 1) {
        int t = __shfl_up(incl, off);
        if (lane >= off) incl += t;
    }
    if (lane == 63) wsum[wid] = incl;
    __syncthreads();
    if (wid == 0) {
        int v = (lane < 16) ? wsum[lane] : 0;
        #pragma unroll
        for (int off = 1; off < 16; off <<= 1) {
            int t = __shfl_up(v, off);
            if (lane >= off) v += t;
        }
        if (lane < 16) wsum[lane] = v;   // inclusive wave sums
    }
    __syncthreads();
    const int woff = (wid > 0) ? wsum[wid - 1] : 0;
    int run = woff + incl - s;           // exclusive prefix at lo
    for (int i = lo; i < hi; ++i) {
        const int d = deg[i];
        row_start[i] = run;
        cursor[i]    = run;
        run += d;
    }
    if (tid == 0) row_start[N] = wsum[15];
}

// ---------------- K4: scatter edges into CSR buckets with scores ----------------
__global__ void k_scatter(const int* __restrict__ ei,
    const float* __restrict__ asrc, const float* __restrict__ adst,
    int* __restrict__ cursor, int* __restrict__ csr_src, float4* __restrict__ csr_score,
    int N, int E0_)
{
    const int e = blockIdx.x * blockDim.x + threadIdx.x;
    const int ea = 2 * E0_ + N;
    if (e >= ea) return;
    int s, d;
    if (e < E0_)          { s = ei[e];        d = ei[E0_ + e]; }
    else if (e < 2 * E0_) { int j = e - E0_;  s = ei[E0_ + j]; d = ei[j]; }
    else                  { s = e - 2 * E0_;  d = s; }
    const float4 as = *(const float4*)(asrc + (size_t)s * NH);
    const float4 ad = *(const float4*)(adst + (size_t)d * NH);
    float4 sc; float v;
    v = as.x + ad.x; sc.x = v > 0.f ? v : 0.2f * v;
    v = as.y + ad.y; sc.y = v > 0.f ? v : 0.2f * v;
    v = as.z + ad.z; sc.z = v > 0.f ? v : 0.2f * v;
    v = as.w + ad.w; sc.w = v > 0.f ? v : 0.2f * v;
    const int pos = atomicAdd(cursor + d, 1);
    csr_src[pos]   = s;
    csr_score[pos] = sc;
}

// ---------------- K5: per-node softmax + weighted aggregation + ELU + Wf dot ----------------
// one wave per node; lane owns feature dims {2*lane, 2*lane+1}; head = lane/16.
__global__ __launch_bounds__(256) void k_agg(
    const float* __restrict__ proj, const int* __restrict__ row_start,
    const int* __restrict__ csr_src, const float4* __restrict__ csr_score,
    const float* __restrict__ b1, const float* __restrict__ Wf, const float* __restrict__ bf,
    float* __restrict__ out, int N)
{
    const int lane = threadIdx.x & 63;
    const int n = blockIdx.x * 4 + (threadIdx.x >> 6);
    if (n >= N) return;
    const int start = row_start[n], end = row_start[n + 1];

    // pass A: per-head max
    float mx0 = -INFINITY, mx1 = -INFINITY, mx2 = -INFINITY, mx3 = -INFINITY;
    for (int e = start + lane; e < end; e += 64) {
        const float4 sc = csr_score[e];
        mx0 = fmaxf(mx0, sc.x); mx1 = fmaxf(mx1, sc.y);
        mx2 = fmaxf(mx2, sc.z); mx3 = fmaxf(mx3, sc.w);
    }
    #pragma unroll
    for (int off = 1; off < 64; off <<= 1) {
        mx0 = fmaxf(mx0, __shfl_xor(mx0, off));
        mx1 = fmaxf(mx1, __shfl_xor(mx1, off));
        mx2 = fmaxf(mx2, __shfl_xor(mx2, off));
        mx3 = fmaxf(mx3, __shfl_xor(mx3, off));
    }
    // pass B: denom
    float dn0 = 0, dn1 = 0, dn2 = 0, dn3 = 0;
    for (int e = start + lane; e < end; e += 64) {
        const float4 sc = csr_score[e];
        dn0 += expf(sc.x - mx0); dn1 += expf(sc.y - mx1);
        dn2 += expf(sc.z - mx2); dn3 += expf(sc.w - mx3);
    }
    dn0 = wave_sum(dn0); dn1 = wave_sum(dn1); dn2 = wave_sum(dn2); dn3 = wave_sum(dn3);
    const float rd0 = 1.f / fmaxf(dn0, 1e-12f);
    const float rd1 = 1.f / fmaxf(dn1, 1e-12f);
    const float rd2 = 1.f / fmaxf(dn2, 1e-12f);
    const float rd3 = 1.f / fmaxf(dn3, 1e-12f);

    const int hl = lane >> 4;
    const float mxh = (hl == 0) ? mx0 : (hl == 1) ? mx1 : (hl == 2) ? mx2 : mx3;
    const float rdh = (hl == 0) ? rd0 : (hl == 1) ? rd1 : (hl == 2) ? rd2 : rd3;
    const int i0 = lane * 2;

    // pass C: weighted gather-accumulate (whole wave per edge, coalesced 512B rows)
    float acc0 = 0.f, acc1 = 0.f;
    for (int e = start; e < end; ++e) {
        const int s = csr_src[e];
        const float sch = ((const float*)(csr_score + e))[hl];
        const float wgt = expf(sch - mxh) * rdh;
        const float2 p = *(const float2*)(proj + (size_t)s * HD + i0);
        acc0 += p.x * wgt; acc1 += p.y * wgt;
    }

    // epilogue: +b1, ELU, dot with Wf, +bf
    float v0 = acc0 + b1[i0], v1 = acc1 + b1[i0 + 1];
    v0 = v0 > 0.f ? v0 : expm1f(v0);
    v1 = v1 > 0.f ? v1 : expm1f(v1);
    float r = v0 * Wf[i0] + v1 * Wf[i0 + 1];
    r = wave_sum(r);
    if (lane == 0) out[n] = r + bf[0];
}

extern "C" void kernel_launch(void* const* d_in, const int* in_sizes, int n_in,
                              void* d_out, int out_size, void* d_ws, size_t ws_size,
                              hipStream_t stream) {
    const float* x     = (const float*)d_in[0];
    const int*   ei    = (const int*)d_in[1];
    const float* W1    = (const float*)d_in[2];
    const float* a_src = (const float*)d_in[3];
    const float* a_dst = (const float*)d_in[4];
    const float* b1    = (const float*)d_in[5];
    const float* Wf    = (const float*)d_in[6];
    const float* bf    = (const float*)d_in[7];
    float* out = (float*)d_out;

    const int N   = in_sizes[0] / HD;     // 50000
    const int E0_ = in_sizes[1] / 2;      // 600000
    const int EA_ = 2 * E0_ + N;          // 1,250,000

    char* w = (char*)d_ws;
    auto alloc = [&](size_t bytes) { char* p = w; w += (bytes + 255) & ~(size_t)255; return p; };
    float*  proj      = (float*)alloc((size_t)N * HD * 4);    // 25.6 MB
    float*  asrc      = (float*)alloc((size_t)N * NH * 4);
    float*  adst      = (float*)alloc((size_t)N * NH * 4);
    int*    deg       = (int*)alloc((size_t)N * 4);
    int*    row_start = (int*)alloc((size_t)(N + 1) * 4);
    int*    cursor    = (int*)alloc((size_t)N * 4);
    int*    csr_src   = (int*)alloc((size_t)EA_ * 4);          // 5 MB
    float4* csr_score = (float4*)alloc((size_t)EA_ * 16);      // 20 MB

    hipMemsetAsync(deg, 0, (size_t)N * 4, stream);

    k_proj<<<(N + 63) / 64, 256, 0, stream>>>(x, W1, a_src, a_dst, proj, asrc, adst, N);
    k_degree<<<(EA_ + 255) / 256, 256, 0, stream>>>(ei, deg, N, E0_);
    k_scan<<<1, 1024, 0, stream>>>(deg, row_start, cursor, N);
    k_scatter<<<(EA_ + 255) / 256, 256, 0, stream>>>(ei, asrc, adst, cursor, csr_src, csr_score, N, E0_);
    k_agg<<<(N + 3) / 4, 256, 0, stream>>>(proj, row_start, csr_src, csr_score, b1, Wf, bf, out, N);
}

// Round 4
// 450.668 us; speedup vs baseline: 1.0940x; 1.0940x over previous
//
#include <hip/hip_runtime.h>
#include <math.h>

#define HD 128   // HEADS*OUT_DIM
#define NH 4     // HEADS

__device__ __forceinline__ float wave_sum(float v) {
    #pragma unroll
    for (int off = 1; off < 64; off <<= 1) v += __shfl_xor(v, off);
    return v;
}
__device__ __forceinline__ float wave_max(float v) {
    #pragma unroll
    for (int off = 1; off < 64; off <<= 1) v = fmaxf(v, __shfl_xor(v, off));
    return v;
}
__device__ __forceinline__ float leaky(float v) { return v > 0.f ? v : 0.2f * v; }

// ---------------- K1: proj = x @ W1 ; alpha_src/alpha_dst per node ----------------
__global__ __launch_bounds__(256) void k_proj(
    const float* __restrict__ x, const float* __restrict__ W1,
    const float* __restrict__ a_src, const float* __restrict__ a_dst,
    float* __restrict__ proj, float* __restrict__ asrc, float* __restrict__ adst, int N)
{
    __shared__ float4 xs[64 * 33];
    const int tid = threadIdx.x;
    const int node0 = blockIdx.x * 64;

    for (int i = tid; i < 64 * 32; i += 256) {
        int r = i >> 5, c = i & 31;
        float4 v = {0.f, 0.f, 0.f, 0.f};
        int n = node0 + r;
        if (n < N) v = *(const float4*)(x + (size_t)n * HD + c * 4);
        xs[r * 33 + c] = v;
    }
    __syncthreads();

    const int ng = tid >> 4;
    const int cg = tid & 15;
    const int c0 = cg * 8;

    float acc[4][8];
    #pragma unroll
    for (int r = 0; r < 4; ++r)
        #pragma unroll
        for (int j = 0; j < 8; ++j) acc[r][j] = 0.f;

    for (int k4 = 0; k4 < 32; ++k4) {
        float4 xv[4];
        #pragma unroll
        for (int r = 0; r < 4; ++r) xv[r] = xs[(ng * 4 + r) * 33 + k4];
        #pragma unroll
        for (int kk = 0; kk < 4; ++kk) {
            const int k = k4 * 4 + kk;
            const float4 w0 = *(const float4*)(W1 + k * HD + c0);
            const float4 w1 = *(const float4*)(W1 + k * HD + c0 + 4);
            #pragma unroll
            for (int r = 0; r < 4; ++r) {
                const float xvk = (kk == 0) ? xv[r].x : (kk == 1) ? xv[r].y : (kk == 2) ? xv[r].z : xv[r].w;
                acc[r][0] += xvk * w0.x; acc[r][1] += xvk * w0.y;
                acc[r][2] += xvk * w0.z; acc[r][3] += xvk * w0.w;
                acc[r][4] += xvk * w1.x; acc[r][5] += xvk * w1.y;
                acc[r][6] += xvk * w1.z; acc[r][7] += xvk * w1.w;
            }
        }
    }

    float as_[8], ad_[8];
    #pragma unroll
    for (int j = 0; j < 8; ++j) { as_[j] = a_src[c0 + j]; ad_[j] = a_dst[c0 + j]; }

    #pragma unroll
    for (int r = 0; r < 4; ++r) {
        const int n = node0 + ng * 4 + r;
        if (n >= N) break;
        float4 o0 = {acc[r][0], acc[r][1], acc[r][2], acc[r][3]};
        float4 o1 = {acc[r][4], acc[r][5], acc[r][6], acc[r][7]};
        *(float4*)(proj + (size_t)n * HD + c0)     = o0;
        *(float4*)(proj + (size_t)n * HD + c0 + 4) = o1;
        float ps = 0.f, pd = 0.f;
        #pragma unroll
        for (int j = 0; j < 8; ++j) { ps += acc[r][j] * as_[j]; pd += acc[r][j] * ad_[j]; }
        ps += __shfl_xor(ps, 1); ps += __shfl_xor(ps, 2);
        pd += __shfl_xor(pd, 1); pd += __shfl_xor(pd, 2);
        if ((cg & 3) == 0) {
            asrc[(size_t)n * NH + (cg >> 2)] = ps;
            adst[(size_t)n * NH + (cg >> 2)] = pd;
        }
    }
}

// ---------------- K2: degree histogram over augmented dst ----------------
__global__ void k_degree(const int* __restrict__ ei, int* __restrict__ deg, int N, int E0_) {
    const int e = blockIdx.x * blockDim.x + threadIdx.x;
    const int ea = 2 * E0_ + N;
    if (e >= ea) return;
    int d;
    if (e < E0_)            d = ei[E0_ + e];
    else if (e < 2 * E0_)   d = ei[e - E0_];
    else                    d = e - 2 * E0_;
    atomicAdd(deg + d, 1);
}

// ---------------- K3: exclusive scan deg -> row_start, cursor ----------------
__global__ __launch_bounds__(1024) void k_scan(
    const int* __restrict__ deg, int* __restrict__ row_start, int* __restrict__ cursor, int N)
{
    __shared__ int wsum[16];
    const int tid = threadIdx.x;
    const int chunk = (N + 1023) >> 10;
    const int lo = tid * chunk;
    const int hi = min(lo + chunk, N);
    int s = 0;
    for (int i = lo; i < hi; ++i) s += deg[i];
    const int lane = tid & 63, wid = tid >> 6;
    int incl = s;
    #pragma unroll
    for (int off = 1; off < 64; off <<= 1) {
        int t = __shfl_up(incl, off);
        if (lane >= off) incl += t;
    }
    if (lane == 63) wsum[wid] = incl;
    __syncthreads();
    if (wid == 0) {
        int v = (lane < 16) ? wsum[lane] : 0;
        #pragma unroll
        for (int off = 1; off < 16; off <<= 1) {
            int t = __shfl_up(v, off);
            if (lane >= off) v += t;
        }
        if (lane < 16) wsum[lane] = v;
    }
    __syncthreads();
    const int woff = (wid > 0) ? wsum[wid - 1] : 0;
    int run = woff + incl - s;
    for (int i = lo; i < hi; ++i) {
        const int d = deg[i];
        row_start[i] = run;
        cursor[i]    = run;
        run += d;
    }
    if (tid == 0) row_start[N] = wsum[15];
}

// ---------------- K4: scatter src ids into CSR buckets (no scores) ----------------
__global__ void k_scatter(const int* __restrict__ ei,
    int* __restrict__ cursor, int* __restrict__ csr_src, int N, int E0_)
{
    const int e = blockIdx.x * blockDim.x + threadIdx.x;
    const int ea = 2 * E0_ + N;
    if (e >= ea) return;
    int s, d;
    if (e < E0_)          { s = ei[e];        d = ei[E0_ + e]; }
    else if (e < 2 * E0_) { int j = e - E0_;  s = ei[E0_ + j]; d = ei[j]; }
    else                  { s = e - 2 * E0_;  d = s; }
    const int pos = atomicAdd(cursor + d, 1);
    csr_src[pos] = s;
}

// ---------------- K5: softmax + aggregation + ELU + Wf dot ----------------
// one wave per node. Fast path deg<=64: lane-parallel score/exp/normalize into
// wave-private LDS, then serial gather loop free of exp (unroll-4 for ILP).
__global__ __launch_bounds__(256) void k_agg(
    const float* __restrict__ proj, const int* __restrict__ row_start,
    const int* __restrict__ csr_src,
    const float* __restrict__ asrc, const float* __restrict__ adst,
    const float* __restrict__ b1, const float* __restrict__ Wf, const float* __restrict__ bf,
    float* __restrict__ out, int N)
{
    __shared__ float4 lw[4][64];   // per-wave normalized weights
    __shared__ int    ls[4][64];   // per-wave src ids
    const int wid  = threadIdx.x >> 6;
    const int lane = threadIdx.x & 63;
    const int n = blockIdx.x * 4 + wid;
    if (n >= N) return;
    const int start = row_start[n], end = row_start[n + 1];
    const int deg = end - start;
    const float4 ad4 = *(const float4*)(adst + (size_t)n * NH);
    const int hl = lane >> 4;
    const int i0 = lane * 2;

    float acc0 = 0.f, acc1 = 0.f;

    if (deg <= 64) {
        const bool live = lane < deg;
        int sl = 0;
        if (live) sl = csr_src[start + lane];
        float4 sc = {-INFINITY, -INFINITY, -INFINITY, -INFINITY};
        if (live) {
            const float4 as4 = *(const float4*)(asrc + (size_t)sl * NH);
            sc.x = leaky(as4.x + ad4.x); sc.y = leaky(as4.y + ad4.y);
            sc.z = leaky(as4.z + ad4.z); sc.w = leaky(as4.w + ad4.w);
        }
        const float m0 = wave_max(sc.x), m1 = wave_max(sc.y);
        const float m2 = wave_max(sc.z), m3 = wave_max(sc.w);
        float4 ex = {0.f, 0.f, 0.f, 0.f};
        if (live) {
            ex.x = expf(sc.x - m0); ex.y = expf(sc.y - m1);
            ex.z = expf(sc.z - m2); ex.w = expf(sc.w - m3);
        }
        const float rd0 = 1.f / fmaxf(wave_sum(ex.x), 1e-12f);
        const float rd1 = 1.f / fmaxf(wave_sum(ex.y), 1e-12f);
        const float rd2 = 1.f / fmaxf(wave_sum(ex.z), 1e-12f);
        const float rd3 = 1.f / fmaxf(wave_sum(ex.w), 1e-12f);
        lw[wid][lane] = make_float4(ex.x * rd0, ex.y * rd1, ex.z * rd2, ex.w * rd3);
        ls[wid][lane] = sl;
        asm volatile("s_waitcnt lgkmcnt(0)" ::: "memory");   // cross-lane LDS handoff, same wave
        #pragma unroll 4
        for (int k = 0; k < deg; ++k) {
            const int s = ls[wid][k];
            const float wgt = ((const float*)&lw[wid][k])[hl];
            const float2 p = *(const float2*)(proj + (size_t)s * HD + i0);
            acc0 += p.x * wgt; acc1 += p.y * wgt;
        }
    } else {
        // generic chunked path (deg > 64 — statistically never, correctness only)
        float m0 = -INFINITY, m1 = -INFINITY, m2 = -INFINITY, m3 = -INFINITY;
        for (int e = start + lane; e < end; e += 64) {
            const int s = csr_src[e];
            const float4 as4 = *(const float4*)(asrc + (size_t)s * NH);
            m0 = fmaxf(m0, leaky(as4.x + ad4.x)); m1 = fmaxf(m1, leaky(as4.y + ad4.y));
            m2 = fmaxf(m2, leaky(as4.z + ad4.z)); m3 = fmaxf(m3, leaky(as4.w + ad4.w));
        }
        m0 = wave_max(m0); m1 = wave_max(m1); m2 = wave_max(m2); m3 = wave_max(m3);
        float dn0 = 0.f, dn1 = 0.f, dn2 = 0.f, dn3 = 0.f;
        for (int e = start + lane; e < end; e += 64) {
            const int s = csr_src[e];
            const float4 as4 = *(const float4*)(asrc + (size_t)s * NH);
            dn0 += expf(leaky(as4.x + ad4.x) - m0);
            dn1 += expf(leaky(as4.y + ad4.y) - m1);
            dn2 += expf(leaky(as4.z + ad4.z) - m2);
            dn3 += expf(leaky(as4.w + ad4.w) - m3);
        }
        const float rd0 = 1.f / fmaxf(wave_sum(dn0), 1e-12f);
        const float rd1 = 1.f / fmaxf(wave_sum(dn1), 1e-12f);
        const float rd2 = 1.f / fmaxf(wave_sum(dn2), 1e-12f);
        const float rd3 = 1.f / fmaxf(wave_sum(dn3), 1e-12f);
        for (int base = start; base < end; base += 64) {
            const int cnt = min(64, end - base);
            int sl = 0; float4 w4 = {0.f, 0.f, 0.f, 0.f};
            if (lane < cnt) {
                sl = csr_src[base + lane];
                const float4 as4 = *(const float4*)(asrc + (size_t)sl * NH);
                w4.x = expf(leaky(as4.x + ad4.x) - m0) * rd0;
                w4.y = expf(leaky(as4.y + ad4.y) - m1) * rd1;
                w4.z = expf(leaky(as4.z + ad4.z) - m2) * rd2;
                w4.w = expf(leaky(as4.w + ad4.w) - m3) * rd3;
            }
            lw[wid][lane] = w4;
            ls[wid][lane] = sl;
            asm volatile("s_waitcnt lgkmcnt(0)" ::: "memory");
            #pragma unroll 4
            for (int k = 0; k < cnt; ++k) {
                const int s = ls[wid][k];
                const float wgt = ((const float*)&lw[wid][k])[hl];
                const float2 p = *(const float2*)(proj + (size_t)s * HD + i0);
                acc0 += p.x * wgt; acc1 += p.y * wgt;
            }
        }
    }

    float v0 = acc0 + b1[i0], v1 = acc1 + b1[i0 + 1];
    v0 = v0 > 0.f ? v0 : expm1f(v0);
    v1 = v1 > 0.f ? v1 : expm1f(v1);
    float r = v0 * Wf[i0] + v1 * Wf[i0 + 1];
    r = wave_sum(r);
    if (lane == 0) out[n] = r + bf[0];
}

extern "C" void kernel_launch(void* const* d_in, const int* in_sizes, int n_in,
                              void* d_out, int out_size, void* d_ws, size_t ws_size,
                              hipStream_t stream) {
    const float* x     = (const float*)d_in[0];
    const int*   ei    = (const int*)d_in[1];
    const float* W1    = (const float*)d_in[2];
    const float* a_src = (const float*)d_in[3];
    const float* a_dst = (const float*)d_in[4];
    const float* b1    = (const float*)d_in[5];
    const float* Wf    = (const float*)d_in[6];
    const float* bf    = (const float*)d_in[7];
    float* out = (float*)d_out;

    const int N   = in_sizes[0] / HD;     // 50000
    const int E0_ = in_sizes[1] / 2;      // 600000
    const int EA_ = 2 * E0_ + N;          // 1,250,000

    char* w = (char*)d_ws;
    auto alloc = [&](size_t bytes) { char* p = w; w += (bytes + 255) & ~(size_t)255; return p; };
    float*  proj      = (float*)alloc((size_t)N * HD * 4);    // 25.6 MB
    float*  asrc      = (float*)alloc((size_t)N * NH * 4);
    float*  adst      = (float*)alloc((size_t)N * NH * 4);
    int*    deg       = (int*)alloc((size_t)N * 4);
    int*    row_start = (int*)alloc((size_t)(N + 1) * 4);
    int*    cursor    = (int*)alloc((size_t)N * 4);
    int*    csr_src   = (int*)alloc((size_t)EA_ * 4);          // 5 MB

    hipMemsetAsync(deg, 0, (size_t)N * 4, stream);

    k_proj<<<(N + 63) / 64, 256, 0, stream>>>(x, W1, a_src, a_dst, proj, asrc, adst, N);
    k_degree<<<(EA_ + 255) / 256, 256, 0, stream>>>(ei, deg, N, E0_);
    k_scan<<<1, 1024, 0, stream>>>(deg, row_start, cursor, N);
    k_scatter<<<(EA_ + 255) / 256, 256, 0, stream>>>(ei, cursor, csr_src, N, E0_);
    k_agg<<<(N + 3) / 4, 256, 0, stream>>>(proj, row_start, csr_src, asrc, adst, b1, Wf, bf, out, N);
}

// Round 5
// 352.758 us; speedup vs baseline: 1.3976x; 1.2776x over previous
//
#include <hip/hip_runtime.h>
#include <math.h>

#define HD 128   // HEADS*OUT_DIM
#define NH 4     // HEADS

__device__ __forceinline__ float wave_sum(float v) {
    #pragma unroll
    for (int off = 1; off < 64; off <<= 1) v += __shfl_xor(v, off);
    return v;
}
__device__ __forceinline__ float wave_max(float v) {
    #pragma unroll
    for (int off = 1; off < 64; off <<= 1) v = fmaxf(v, __shfl_xor(v, off));
    return v;
}
__device__ __forceinline__ float leaky(float v) { return v > 0.f ? v : 0.2f * v; }

// block-wide exclusive scan over 256 threads (4 waves); wsum must hold >=4 ints
__device__ __forceinline__ int block_excl_scan_256(int v, int tid, int* wsum) {
    const int lane = tid & 63, w = tid >> 6;
    int incl = v;
    #pragma unroll
    for (int off = 1; off < 64; off <<= 1) {
        int t = __shfl_up(incl, off);
        if (lane >= off) incl += t;
    }
    if (lane == 63) wsum[w] = incl;
    __syncthreads();
    int woff = 0;
    #pragma unroll
    for (int i = 0; i < 3; ++i) if (i < w) woff += wsum[i];
    return woff + incl - v;
}

// ---------------- K1: proj = x @ W1 ; alpha_src/alpha_dst per node ----------------
__global__ __launch_bounds__(256) void k_proj(
    const float* __restrict__ x, const float* __restrict__ W1,
    const float* __restrict__ a_src, const float* __restrict__ a_dst,
    float* __restrict__ proj, float* __restrict__ asrc, float* __restrict__ adst, int N)
{
    __shared__ float4 xs[64 * 33];
    const int tid = threadIdx.x;
    const int node0 = blockIdx.x * 64;

    for (int i = tid; i < 64 * 32; i += 256) {
        int r = i >> 5, c = i & 31;
        float4 v = {0.f, 0.f, 0.f, 0.f};
        int n = node0 + r;
        if (n < N) v = *(const float4*)(x + (size_t)n * HD + c * 4);
        xs[r * 33 + c] = v;
    }
    __syncthreads();

    const int ng = tid >> 4;
    const int cg = tid & 15;
    const int c0 = cg * 8;

    float acc[4][8];
    #pragma unroll
    for (int r = 0; r < 4; ++r)
        #pragma unroll
        for (int j = 0; j < 8; ++j) acc[r][j] = 0.f;

    for (int k4 = 0; k4 < 32; ++k4) {
        float4 xv[4];
        #pragma unroll
        for (int r = 0; r < 4; ++r) xv[r] = xs[(ng * 4 + r) * 33 + k4];
        #pragma unroll
        for (int kk = 0; kk < 4; ++kk) {
            const int k = k4 * 4 + kk;
            const float4 w0 = *(const float4*)(W1 + k * HD + c0);
            const float4 w1 = *(const float4*)(W1 + k * HD + c0 + 4);
            #pragma unroll
            for (int r = 0; r < 4; ++r) {
                const float xvk = (kk == 0) ? xv[r].x : (kk == 1) ? xv[r].y : (kk == 2) ? xv[r].z : xv[r].w;
                acc[r][0] += xvk * w0.x; acc[r][1] += xvk * w0.y;
                acc[r][2] += xvk * w0.z; acc[r][3] += xvk * w0.w;
                acc[r][4] += xvk * w1.x; acc[r][5] += xvk * w1.y;
                acc[r][6] += xvk * w1.z; acc[r][7] += xvk * w1.w;
            }
        }
    }

    float as_[8], ad_[8];
    #pragma unroll
    for (int j = 0; j < 8; ++j) { as_[j] = a_src[c0 + j]; ad_[j] = a_dst[c0 + j]; }

    #pragma unroll
    for (int r = 0; r < 4; ++r) {
        const int n = node0 + ng * 4 + r;
        if (n >= N) break;
        float4 o0 = {acc[r][0], acc[r][1], acc[r][2], acc[r][3]};
        float4 o1 = {acc[r][4], acc[r][5], acc[r][6], acc[r][7]};
        *(float4*)(proj + (size_t)n * HD + c0)     = o0;
        *(float4*)(proj + (size_t)n * HD + c0 + 4) = o1;
        float ps = 0.f, pd = 0.f;
        #pragma unroll
        for (int j = 0; j < 8; ++j) { ps += acc[r][j] * as_[j]; pd += acc[r][j] * ad_[j]; }
        ps += __shfl_xor(ps, 1); ps += __shfl_xor(ps, 2);
        pd += __shfl_xor(pd, 1); pd += __shfl_xor(pd, 2);
        if ((cg & 3) == 0) {
            asrc[(size_t)n * NH + (cg >> 2)] = ps;
            adst[(size_t)n * NH + (cg >> 2)] = pd;
        }
    }
}

// ---------------- K2: degree histogram over augmented dst ----------------
__global__ void k_degree(const int* __restrict__ ei, int* __restrict__ deg, int N, int E0_) {
    const int e = blockIdx.x * blockDim.x + threadIdx.x;
    const int ea = 2 * E0_ + N;
    if (e >= ea) return;
    int d;
    if (e < E0_)            d = ei[E0_ + e];
    else if (e < 2 * E0_)   d = ei[e - E0_];
    else                    d = e - 2 * E0_;
    atomicAdd(deg + d, 1);
}

// ---------------- K3a: per-block sums of deg ----------------
__global__ __launch_bounds__(256) void k_bsum(
    const int* __restrict__ deg, int* __restrict__ bsum, int N)
{
    __shared__ int wsum[4];
    const int tid = threadIdx.x;
    const int gid = blockIdx.x * 256 + tid;
    int v = (gid < N) ? deg[gid] : 0;
    int s = v;
    #pragma unroll
    for (int off = 1; off < 64; off <<= 1) s += __shfl_xor(s, off);
    if ((tid & 63) == 0) wsum[tid >> 6] = s;
    __syncthreads();
    if (tid == 0) bsum[blockIdx.x] = wsum[0] + wsum[1] + wsum[2] + wsum[3];
}

// ---------------- K3b: exclusive scan of block sums (NB <= 256) ----------------
__global__ __launch_bounds__(256) void k_bscan(
    const int* __restrict__ bsum, int* __restrict__ boff,
    int* __restrict__ row_start, int NB, int N)
{
    __shared__ int wsum[4];
    const int tid = threadIdx.x;
    const int v = (tid < NB) ? bsum[tid] : 0;
    const int excl = block_excl_scan_256(v, tid, wsum);
    if (tid < NB) boff[tid] = excl;
    if (tid == 255) row_start[N] = excl + v;   // grand total
}

// ---------------- K3c: per-block exclusive scan + offset -> row_start, cursor ----------------
__global__ __launch_bounds__(256) void k_scan2(
    const int* __restrict__ deg, const int* __restrict__ boff,
    int* __restrict__ row_start, int* __restrict__ cursor, int N)
{
    __shared__ int wsum[4];
    const int tid = threadIdx.x;
    const int gid = blockIdx.x * 256 + tid;
    const int v = (gid < N) ? deg[gid] : 0;
    const int excl = block_excl_scan_256(v, tid, wsum) + boff[blockIdx.x];
    if (gid < N) { row_start[gid] = excl; cursor[gid] = excl; }
}

// ---------------- K4: scatter src ids into CSR buckets ----------------
__global__ void k_scatter(const int* __restrict__ ei,
    int* __restrict__ cursor, int* __restrict__ csr_src, int N, int E0_)
{
    const int e = blockIdx.x * blockDim.x + threadIdx.x;
    const int ea = 2 * E0_ + N;
    if (e >= ea) return;
    int s, d;
    if (e < E0_)          { s = ei[e];        d = ei[E0_ + e]; }
    else if (e < 2 * E0_) { int j = e - E0_;  s = ei[E0_ + j]; d = ei[j]; }
    else                  { s = e - 2 * E0_;  d = s; }
    const int pos = atomicAdd(cursor + d, 1);
    csr_src[pos] = s;
}

// ---------------- K5: softmax + aggregation + ELU + Wf dot ----------------
__global__ __launch_bounds__(256) void k_agg(
    const float* __restrict__ proj, const int* __restrict__ row_start,
    const int* __restrict__ csr_src,
    const float* __restrict__ asrc, const float* __restrict__ adst,
    const float* __restrict__ b1, const float* __restrict__ Wf, const float* __restrict__ bf,
    float* __restrict__ out, int N)
{
    __shared__ float4 lw[4][64];   // per-wave normalized weights
    __shared__ int    ls[4][64];   // per-wave src ids
    const int wid  = threadIdx.x >> 6;
    const int lane = threadIdx.x & 63;
    const int n = blockIdx.x * 4 + wid;
    if (n >= N) return;
    const int start = row_start[n], end = row_start[n + 1];
    const int deg = end - start;
    const float4 ad4 = *(const float4*)(adst + (size_t)n * NH);
    const int hl = lane >> 4;
    const int i0 = lane * 2;

    float acc0 = 0.f, acc1 = 0.f;

    if (deg <= 64) {
        const bool live = lane < deg;
        int sl = 0;
        if (live) sl = csr_src[start + lane];
        float4 sc = {-INFINITY, -INFINITY, -INFINITY, -INFINITY};
        if (live) {
            const float4 as4 = *(const float4*)(asrc + (size_t)sl * NH);
            sc.x = leaky(as4.x + ad4.x); sc.y = leaky(as4.y + ad4.y);
            sc.z = leaky(as4.z + ad4.z); sc.w = leaky(as4.w + ad4.w);
        }
        const float m0 = wave_max(sc.x), m1 = wave_max(sc.y);
        const float m2 = wave_max(sc.z), m3 = wave_max(sc.w);
        float4 ex = {0.f, 0.f, 0.f, 0.f};
        if (live) {
            ex.x = expf(sc.x - m0); ex.y = expf(sc.y - m1);
            ex.z = expf(sc.z - m2); ex.w = expf(sc.w - m3);
        }
        const float rd0 = 1.f / fmaxf(wave_sum(ex.x), 1e-12f);
        const float rd1 = 1.f / fmaxf(wave_sum(ex.y), 1e-12f);
        const float rd2 = 1.f / fmaxf(wave_sum(ex.z), 1e-12f);
        const float rd3 = 1.f / fmaxf(wave_sum(ex.w), 1e-12f);
        lw[wid][lane] = make_float4(ex.x * rd0, ex.y * rd1, ex.z * rd2, ex.w * rd3);
        ls[wid][lane] = sl;
        asm volatile("s_waitcnt lgkmcnt(0)" ::: "memory");   // cross-lane LDS handoff, same wave
        #pragma unroll 4
        for (int k = 0; k < deg; ++k) {
            const int s = ls[wid][k];
            const float wgt = ((const float*)&lw[wid][k])[hl];
            const float2 p = *(const float2*)(proj + (size_t)s * HD + i0);
            acc0 += p.x * wgt; acc1 += p.y * wgt;
        }
    } else {
        float m0 = -INFINITY, m1 = -INFINITY, m2 = -INFINITY, m3 = -INFINITY;
        for (int e = start + lane; e < end; e += 64) {
            const int s = csr_src[e];
            const float4 as4 = *(const float4*)(asrc + (size_t)s * NH);
            m0 = fmaxf(m0, leaky(as4.x + ad4.x)); m1 = fmaxf(m1, leaky(as4.y + ad4.y));
            m2 = fmaxf(m2, leaky(as4.z + ad4.z)); m3 = fmaxf(m3, leaky(as4.w + ad4.w));
        }
        m0 = wave_max(m0); m1 = wave_max(m1); m2 = wave_max(m2); m3 = wave_max(m3);
        float dn0 = 0.f, dn1 = 0.f, dn2 = 0.f, dn3 = 0.f;
        for (int e = start + lane; e < end; e += 64) {
            const int s = csr_src[e];
            const float4 as4 = *(const float4*)(asrc + (size_t)s * NH);
            dn0 += expf(leaky(as4.x + ad4.x) - m0);
            dn1 += expf(leaky(as4.y + ad4.y) - m1);
            dn2 += expf(leaky(as4.z + ad4.z) - m2);
            dn3 += expf(leaky(as4.w + ad4.w) - m3);
        }
        const float rd0 = 1.f / fmaxf(wave_sum(dn0), 1e-12f);
        const float rd1 = 1.f / fmaxf(wave_sum(dn1), 1e-12f);
        const float rd2 = 1.f / fmaxf(wave_sum(dn2), 1e-12f);
        const float rd3 = 1.f / fmaxf(wave_sum(dn3), 1e-12f);
        for (int base = start; base < end; base += 64) {
            const int cnt = min(64, end - base);
            int sl = 0; float4 w4 = {0.f, 0.f, 0.f, 0.f};
            if (lane < cnt) {
                sl = csr_src[base + lane];
                const float4 as4 = *(const float4*)(asrc + (size_t)sl * NH);
                w4.x = expf(leaky(as4.x + ad4.x) - m0) * rd0;
                w4.y = expf(leaky(as4.y + ad4.y) - m1) * rd1;
                w4.z = expf(leaky(as4.z + ad4.z) - m2) * rd2;
                w4.w = expf(leaky(as4.w + ad4.w) - m3) * rd3;
            }
            lw[wid][lane] = w4;
            ls[wid][lane] = sl;
            asm volatile("s_waitcnt lgkmcnt(0)" ::: "memory");
            #pragma unroll 4
            for (int k = 0; k < cnt; ++k) {
                const int s = ls[wid][k];
                const float wgt = ((const float*)&lw[wid][k])[hl];
                const float2 p = *(const float2*)(proj + (size_t)s * HD + i0);
                acc0 += p.x * wgt; acc1 += p.y * wgt;
            }
        }
    }

    float v0 = acc0 + b1[i0], v1 = acc1 + b1[i0 + 1];
    v0 = v0 > 0.f ? v0 : expm1f(v0);
    v1 = v1 > 0.f ? v1 : expm1f(v1);
    float r = v0 * Wf[i0] + v1 * Wf[i0 + 1];
    r = wave_sum(r);
    if (lane == 0) out[n] = r + bf[0];
}

extern "C" void kernel_launch(void* const* d_in, const int* in_sizes, int n_in,
                              void* d_out, int out_size, void* d_ws, size_t ws_size,
                              hipStream_t stream) {
    const float* x     = (const float*)d_in[0];
    const int*   ei    = (const int*)d_in[1];
    const float* W1    = (const float*)d_in[2];
    const float* a_src = (const float*)d_in[3];
    const float* a_dst = (const float*)d_in[4];
    const float* b1    = (const float*)d_in[5];
    const float* Wf    = (const float*)d_in[6];
    const float* bf    = (const float*)d_in[7];
    float* out = (float*)d_out;

    const int N   = in_sizes[0] / HD;     // 50000
    const int E0_ = in_sizes[1] / 2;      // 600000
    const int EA_ = 2 * E0_ + N;          // 1,250,000
    const int NB  = (N + 255) / 256;      // 196 scan blocks

    char* w = (char*)d_ws;
    auto alloc = [&](size_t bytes) { char* p = w; w += (bytes + 255) & ~(size_t)255; return p; };
    float*  proj      = (float*)alloc((size_t)N * HD * 4);    // 25.6 MB
    float*  asrc      = (float*)alloc((size_t)N * NH * 4);
    float*  adst      = (float*)alloc((size_t)N * NH * 4);
    int*    deg       = (int*)alloc((size_t)N * 4);
    int*    row_start = (int*)alloc((size_t)(N + 1) * 4);
    int*    cursor    = (int*)alloc((size_t)N * 4);
    int*    csr_src   = (int*)alloc((size_t)EA_ * 4);          // 5 MB
    int*    bsum      = (int*)alloc((size_t)NB * 4);
    int*    boff      = (int*)alloc((size_t)NB * 4);

    hipMemsetAsync(deg, 0, (size_t)N * 4, stream);

    k_proj<<<(N + 63) / 64, 256, 0, stream>>>(x, W1, a_src, a_dst, proj, asrc, adst, N);
    k_degree<<<(EA_ + 255) / 256, 256, 0, stream>>>(ei, deg, N, E0_);
    k_bsum<<<NB, 256, 0, stream>>>(deg, bsum, N);
    k_bscan<<<1, 256, 0, stream>>>(bsum, boff, row_start, NB, N);
    k_scan2<<<NB, 256, 0, stream>>>(deg, boff, row_start, cursor, N);
    k_scatter<<<(EA_ + 255) / 256, 256, 0, stream>>>(ei, cursor, csr_src, N, E0_);
    k_agg<<<(N + 3) / 4, 256, 0, stream>>>(proj, row_start, csr_src, asrc, adst, b1, Wf, bf, out, N);
}

// Round 7
// 300.560 us; speedup vs baseline: 1.6403x; 1.1737x over previous
//
#include <hip/hip_runtime.h>
#include <math.h>

#define HD 128   // HEADS*OUT_DIM
#define NH 4     // HEADS
#define SC_CHUNK 8192   // edges per k_scatter1 block

__device__ __forceinline__ float wave_sum(float v) {
    #pragma unroll
    for (int off = 1; off < 64; off <<= 1) v += __shfl_xor(v, off);
    return v;
}
__device__ __forceinline__ float wave_max(float v) {
    #pragma unroll
    for (int off = 1; off < 64; off <<= 1) v = fmaxf(v, __shfl_xor(v, off));
    return v;
}
__device__ __forceinline__ float leaky(float v) { return v > 0.f ? v : 0.2f * v; }

__device__ __forceinline__ void decode_edge(int e, int E0_, const int* __restrict__ ei,
                                            int& s, int& d) {
    if (e < E0_)          { s = ei[e];        d = ei[E0_ + e]; }
    else if (e < 2 * E0_) { int j = e - E0_;  s = ei[E0_ + j]; d = ei[j]; }
    else                  { s = e - 2 * E0_;  d = s; }
}

// block-wide exclusive scan over 256 threads (4 waves); wsum must hold >=4 ints
__device__ __forceinline__ int block_excl_scan_256(int v, int tid, int* wsum) {
    const int lane = tid & 63, w = tid >> 6;
    int incl = v;
    #pragma unroll
    for (int off = 1; off < 64; off <<= 1) {
        int t = __shfl_up(incl, off);
        if (lane >= off) incl += t;
    }
    if (lane == 63) wsum[w] = incl;
    __syncthreads();
    int woff = 0;
    #pragma unroll
    for (int i = 0; i < 3; ++i) if (i < w) woff += wsum[i];
    return woff + incl - v;
}

// ---------------- K1: proj = x @ W1 ; alpha_src/alpha_dst per node ----------------
__global__ __launch_bounds__(256) void k_proj(
    const float* __restrict__ x, const float* __restrict__ W1,
    const float* __restrict__ a_src, const float* __restrict__ a_dst,
    float* __restrict__ proj, float* __restrict__ asrc, float* __restrict__ adst, int N)
{
    __shared__ float4 xs[64 * 33];
    const int tid = threadIdx.x;
    const int node0 = blockIdx.x * 64;

    for (int i = tid; i < 64 * 32; i += 256) {
        int r = i >> 5, c = i & 31;
        float4 v = {0.f, 0.f, 0.f, 0.f};
        int n = node0 + r;
        if (n < N) v = *(const float4*)(x + (size_t)n * HD + c * 4);
        xs[r * 33 + c] = v;
    }
    __syncthreads();

    const int ng = tid >> 4;
    const int cg = tid & 15;
    const int c0 = cg * 8;

    float acc[4][8];
    #pragma unroll
    for (int r = 0; r < 4; ++r)
        #pragma unroll
        for (int j = 0; j < 8; ++j) acc[r][j] = 0.f;

    for (int k4 = 0; k4 < 32; ++k4) {
        float4 xv[4];
        #pragma unroll
        for (int r = 0; r < 4; ++r) xv[r] = xs[(ng * 4 + r) * 33 + k4];
        #pragma unroll
        for (int kk = 0; kk < 4; ++kk) {
            const int k = k4 * 4 + kk;
            const float4 w0 = *(const float4*)(W1 + k * HD + c0);
            const float4 w1 = *(const float4*)(W1 + k * HD + c0 + 4);
            #pragma unroll
            for (int r = 0; r < 4; ++r) {
                const float xvk = (kk == 0) ? xv[r].x : (kk == 1) ? xv[r].y : (kk == 2) ? xv[r].z : xv[r].w;
                acc[r][0] += xvk * w0.x; acc[r][1] += xvk * w0.y;
                acc[r][2] += xvk * w0.z; acc[r][3] += xvk * w0.w;
                acc[r][4] += xvk * w1.x; acc[r][5] += xvk * w1.y;
                acc[r][6] += xvk * w1.z; acc[r][7] += xvk * w1.w;
            }
        }
    }

    float as_[8], ad_[8];
    #pragma unroll
    for (int j = 0; j < 8; ++j) { as_[j] = a_src[c0 + j]; ad_[j] = a_dst[c0 + j]; }

    #pragma unroll
    for (int r = 0; r < 4; ++r) {
        const int n = node0 + ng * 4 + r;
        if (n >= N) break;
        float4 o0 = {acc[r][0], acc[r][1], acc[r][2], acc[r][3]};
        float4 o1 = {acc[r][4], acc[r][5], acc[r][6], acc[r][7]};
        *(float4*)(proj + (size_t)n * HD + c0)     = o0;
        *(float4*)(proj + (size_t)n * HD + c0 + 4) = o1;
        float ps = 0.f, pd = 0.f;
        #pragma unroll
        for (int j = 0; j < 8; ++j) { ps += acc[r][j] * as_[j]; pd += acc[r][j] * ad_[j]; }
        ps += __shfl_xor(ps, 1); ps += __shfl_xor(ps, 2);
        pd += __shfl_xor(pd, 1); pd += __shfl_xor(pd, 2);
        if ((cg & 3) == 0) {
            asrc[(size_t)n * NH + (cg >> 2)] = ps;
            adst[(size_t)n * NH + (cg >> 2)] = pd;
        }
    }
}

// ---------------- K2: degree histogram over augmented dst ----------------
__global__ void k_degree(const int* __restrict__ ei, int* __restrict__ deg, int N, int E0_) {
    const int e = blockIdx.x * blockDim.x + threadIdx.x;
    const int ea = 2 * E0_ + N;
    if (e >= ea) return;
    int s, d;
    decode_edge(e, E0_, ei, s, d);
    atomicAdd(deg + d, 1);
}

// ---------------- K3a: per-block (=per-bucket, 256 nodes) sums of deg ----------------
__global__ __launch_bounds__(256) void k_bsum(
    const int* __restrict__ deg, int* __restrict__ bsum, int N)
{
    __shared__ int wsum[4];
    const int tid = threadIdx.x;
    const int gid = blockIdx.x * 256 + tid;
    int v = (gid < N) ? deg[gid] : 0;
    int s = v;
    #pragma unroll
    for (int off = 1; off < 64; off <<= 1) s += __shfl_xor(s, off);
    if ((tid & 63) == 0) wsum[tid >> 6] = s;
    __syncthreads();
    if (tid == 0) bsum[blockIdx.x] = wsum[0] + wsum[1] + wsum[2] + wsum[3];
}

// ---------------- K3b: exclusive scan of bucket sums (NB < 256) ----------------
__global__ __launch_bounds__(256) void k_bscan(
    const int* __restrict__ bsum, int* __restrict__ boff, int* __restrict__ bcur,
    int* __restrict__ row_start, int NB, int N)
{
    __shared__ int wsum[4];
    const int tid = threadIdx.x;
    const int v = (tid < NB) ? bsum[tid] : 0;
    const int excl = block_excl_scan_256(v, tid, wsum);
    if (tid < NB) { boff[tid] = excl; bcur[tid] = excl; }
    if (tid == NB) boff[NB] = excl;            // total (v==0 past NB)
    if (tid == 255) row_start[N] = excl + v;   // grand total
}

// ---------------- K3c: per-bucket exclusive scan + offset -> row_start ----------------
__global__ __launch_bounds__(256) void k_scan2(
    const int* __restrict__ deg, const int* __restrict__ boff,
    int* __restrict__ row_start, int N)
{
    __shared__ int wsum[4];
    const int tid = threadIdx.x;
    const int gid = blockIdx.x * 256 + tid;
    const int v = (gid < N) ? deg[gid] : 0;
    const int excl = block_excl_scan_256(v, tid, wsum) + boff[blockIdx.x];
    if (gid < N) row_start[gid] = excl;
}

// ---------------- K4a: bucket-binning scatter (block-privatized reservations) ----------
// Writes (s,d) pairs grouped by bucket (dst>>8). Per-block contiguous runs -> full-line
// writes from a single XCD, killing the 16x partial-line write amplification.
__global__ __launch_bounds__(256) void k_scatter1(
    const int* __restrict__ ei, int* __restrict__ bcur, int2* __restrict__ pair,
    int N, int E0_, int NB)
{
    __shared__ int h[256];
    __shared__ int base[256];
    const int tid = threadIdx.x;
    const int ea = 2 * E0_ + N;
    const int e0 = blockIdx.x * SC_CHUNK;
    const int e1 = min(e0 + SC_CHUNK, ea);

    h[tid] = 0;
    __syncthreads();
    for (int e = e0 + tid; e < e1; e += 256) {
        int s, d; decode_edge(e, E0_, ei, s, d);
        atomicAdd(&h[d >> 8], 1);
    }
    __syncthreads();
    if (tid < NB && h[tid] > 0) base[tid] = atomicAdd(&bcur[tid], h[tid]);
    __syncthreads();
    h[tid] = 0;
    __syncthreads();
    for (int e = e0 + tid; e < e1; e += 256) {
        int s, d; decode_edge(e, E0_, ei, s, d);
        const int b = d >> 8;
        const int r = atomicAdd(&h[b], 1);
        pair[base[b] + r] = make_int2(s, d);
    }
}

// ---------------- K4b: within-bucket placement via LDS cursors (no global atomics) ----
__global__ __launch_bounds__(256) void k_place(
    const int2* __restrict__ pair, const int* __restrict__ boff,
    const int* __restrict__ row_start, int* __restrict__ csr_src, int N)
{
    __shared__ int c[256];
    const int tid = threadIdx.x;
    const int b = blockIdx.x;
    const int node = b * 256 + tid;
    c[tid] = (node < N) ? row_start[node] : 0;
    __syncthreads();
    const int lo = boff[b], hi = boff[b + 1];
    for (int i = lo + tid; i < hi; i += 256) {
        const int2 p = pair[i];
        const int pos = atomicAdd(&c[p.y & 255], 1);
        csr_src[pos] = p.x;
    }
}

// ---------------- K5: softmax + aggregation + ELU + Wf dot ----------------
__global__ __launch_bounds__(256) void k_agg(
    const float* __restrict__ proj, const int* __restrict__ row_start,
    const int* __restrict__ csr_src,
    const float* __restrict__ asrc, const float* __restrict__ adst,
    const float* __restrict__ b1, const float* __restrict__ Wf, const float* __restrict__ bf,
    float* __restrict__ out, int N)
{
    __shared__ float4 lw[4][64];   // per-wave normalized weights
    __shared__ int    ls[4][64];   // per-wave src ids
    const int wid  = threadIdx.x >> 6;
    const int lane = threadIdx.x & 63;
    const int n = blockIdx.x * 4 + wid;
    if (n >= N) return;
    const int start = row_start[n], end = row_start[n + 1];
    const int deg = end - start;
    const float4 ad4 = *(const float4*)(adst + (size_t)n * NH);
    const int hl = lane >> 4;
    const int i0 = lane * 2;

    float acc0 = 0.f, acc1 = 0.f;

    if (deg <= 64) {
        const bool live = lane < deg;
        int sl = 0;
        if (live) sl = csr_src[start + lane];
        float4 sc = {-INFINITY, -INFINITY, -INFINITY, -INFINITY};
        if (live) {
            const float4 as4 = *(const float4*)(asrc + (size_t)sl * NH);
            sc.x = leaky(as4.x + ad4.x); sc.y = leaky(as4.y + ad4.y);
            sc.z = leaky(as4.z + ad4.z); sc.w = leaky(as4.w + ad4.w);
        }
        const float m0 = wave_max(sc.x), m1 = wave_max(sc.y);
        const float m2 = wave_max(sc.z), m3 = wave_max(sc.w);
        float4 ex = {0.f, 0.f, 0.f, 0.f};
        if (live) {
            ex.x = expf(sc.x - m0); ex.y = expf(sc.y - m1);
            ex.z = expf(sc.z - m2); ex.w = expf(sc.w - m3);
        }
        const float rd0 = 1.f / fmaxf(wave_sum(ex.x), 1e-12f);
        const float rd1 = 1.f / fmaxf(wave_sum(ex.y), 1e-12f);
        const float rd2 = 1.f / fmaxf(wave_sum(ex.z), 1e-12f);
        const float rd3 = 1.f / fmaxf(wave_sum(ex.w), 1e-12f);
        lw[wid][lane] = make_float4(ex.x * rd0, ex.y * rd1, ex.z * rd2, ex.w * rd3);
        ls[wid][lane] = sl;
        asm volatile("s_waitcnt lgkmcnt(0)" ::: "memory");   // cross-lane LDS handoff, same wave
        #pragma unroll 4
        for (int k = 0; k < deg; ++k) {
            const int s = ls[wid][k];
            const float wgt = ((const float*)&lw[wid][k])[hl];
            const float2 p = *(const float2*)(proj + (size_t)s * HD + i0);
            acc0 += p.x * wgt; acc1 += p.y * wgt;
        }
    } else {
        float m0 = -INFINITY, m1 = -INFINITY, m2 = -INFINITY, m3 = -INFINITY;
        for (int e = start + lane; e < end; e += 64) {
            const int s = csr_src[e];
            const float4 as4 = *(const float4*)(asrc + (size_t)s * NH);
            m0 = fmaxf(m0, leaky(as4.x + ad4.x)); m1 = fmaxf(m1, leaky(as4.y + ad4.y));
            m2 = fmaxf(m2, leaky(as4.z + ad4.z)); m3 = fmaxf(m3, leaky(as4.w + ad4.w));
        }
        m0 = wave_max(m0); m1 = wave_max(m1); m2 = wave_max(m2); m3 = wave_max(m3);
        float dn0 = 0.f, dn1 = 0.f, dn2 = 0.f, dn3 = 0.f;
        for (int e = start + lane; e < end; e += 64) {
            const int s = csr_src[e];
            const float4 as4 = *(const float4*)(asrc + (size_t)s * NH);
            dn0 += expf(leaky(as4.x + ad4.x) - m0);
            dn1 += expf(leaky(as4.y + ad4.y) - m1);
            dn2 += expf(leaky(as4.z + ad4.z) - m2);
            dn3 += expf(leaky(as4.w + ad4.w) - m3);
        }
        const float rd0 = 1.f / fmaxf(wave_sum(dn0), 1e-12f);
        const float rd1 = 1.f / fmaxf(wave_sum(dn1), 1e-12f);
        const float rd2 = 1.f / fmaxf(wave_sum(dn2), 1e-12f);
        const float rd3 = 1.f / fmaxf(wave_sum(dn3), 1e-12f);
        for (int base = start; base < end; base += 64) {
            const int cnt = min(64, end - base);
            int sl = 0; float4 w4 = {0.f, 0.f, 0.f, 0.f};
            if (lane < cnt) {
                sl = csr_src[base + lane];
                const float4 as4 = *(const float4*)(asrc + (size_t)sl * NH);
                w4.x = expf(leaky(as4.x + ad4.x) - m0) * rd0;
                w4.y = expf(leaky(as4.y + ad4.y) - m1) * rd1;
                w4.z = expf(leaky(as4.z + ad4.z) - m2) * rd2;
                w4.w = expf(leaky(as4.w + ad4.w) - m3) * rd3;
            }
            lw[wid][lane] = w4;
            ls[wid][lane] = sl;
            asm volatile("s_waitcnt lgkmcnt(0)" ::: "memory");
            #pragma unroll 4
            for (int k = 0; k < cnt; ++k) {
                const int s = ls[wid][k];
                const float wgt = ((const float*)&lw[wid][k])[hl];
                const float2 p = *(const float2*)(proj + (size_t)s * HD + i0);
                acc0 += p.x * wgt; acc1 += p.y * wgt;
            }
        }
    }

    float v0 = acc0 + b1[i0], v1 = acc1 + b1[i0 + 1];
    v0 = v0 > 0.f ? v0 : expm1f(v0);
    v1 = v1 > 0.f ? v1 : expm1f(v1);
    float r = v0 * Wf[i0] + v1 * Wf[i0 + 1];
    r = wave_sum(r);
    if (lane == 0) out[n] = r + bf[0];
}

extern "C" void kernel_launch(void* const* d_in, const int* in_sizes, int n_in,
                              void* d_out, int out_size, void* d_ws, size_t ws_size,
                              hipStream_t stream) {
    const float* x     = (const float*)d_in[0];
    const int*   ei    = (const int*)d_in[1];
    const float* W1    = (const float*)d_in[2];
    const float* a_src = (const float*)d_in[3];
    const float* a_dst = (const float*)d_in[4];
    const float* b1    = (const float*)d_in[5];
    const float* Wf    = (const float*)d_in[6];
    const float* bf    = (const float*)d_in[7];
    float* out = (float*)d_out;

    const int N   = in_sizes[0] / HD;     // 50000
    const int E0_ = in_sizes[1] / 2;      // 600000
    const int EA_ = 2 * E0_ + N;          // 1,250,000
    const int NB  = (N + 255) / 256;      // 196 buckets (256 nodes each); NB < 256

    char* w = (char*)d_ws;
    auto alloc = [&](size_t bytes) { char* p = w; w += (bytes + 255) & ~(size_t)255; return p; };
    float*  proj      = (float*)alloc((size_t)N * HD * 4);    // 25.6 MB
    float*  asrc      = (float*)alloc((size_t)N * NH * 4);
    float*  adst      = (float*)alloc((size_t)N * NH * 4);
    int*    deg       = (int*)alloc((size_t)N * 4);
    int*    row_start = (int*)alloc((size_t)(N + 1) * 4);
    int*    csr_src   = (int*)alloc((size_t)EA_ * 4);          // 5 MB
    int2*   pair      = (int2*)alloc((size_t)EA_ * 8);         // 10 MB
    int*    bsum      = (int*)alloc((size_t)NB * 4);
    int*    boff      = (int*)alloc((size_t)(NB + 1) * 4);
    int*    bcur      = (int*)alloc((size_t)NB * 4);

    hipMemsetAsync(deg, 0, (size_t)N * 4, stream);

    k_proj<<<(N + 63) / 64, 256, 0, stream>>>(x, W1, a_src, a_dst, proj, asrc, adst, N);
    k_degree<<<(EA_ + 255) / 256, 256, 0, stream>>>(ei, deg, N, E0_);
    k_bsum<<<NB, 256, 0, stream>>>(deg, bsum, N);
    k_bscan<<<1, 256, 0, stream>>>(bsum, boff, bcur, row_start, NB, N);
    k_scan2<<<NB, 256, 0, stream>>>(deg, boff, row_start, N);
    k_scatter1<<<(EA_ + SC_CHUNK - 1) / SC_CHUNK, 256, 0, stream>>>(ei, bcur, pair, N, E0_, NB);
    k_place<<<NB, 256, 0, stream>>>(pair, boff, row_start, csr_src, N);
    k_agg<<<(N + 3) / 4, 256, 0, stream>>>(proj, row_start, csr_src, asrc, adst, b1, Wf, bf, out, N);
}

// Round 8
// 270.169 us; speedup vs baseline: 1.8249x; 1.1125x over previous
//
#include <hip/hip_runtime.h>
#include <hip/hip_fp16.h>
#include <math.h>

#define HD 128   // HEADS*OUT_DIM
#define NH 4     // HEADS
#define SC_CHUNK 8192   // edges per k_scatter1 block

__device__ __forceinline__ float wave_sum(float v) {
    #pragma unroll
    for (int off = 1; off < 64; off <<= 1) v += __shfl_xor(v, off);
    return v;
}
__device__ __forceinline__ float wave_max(float v) {
    #pragma unroll
    for (int off = 1; off < 64; off <<= 1) v = fmaxf(v, __shfl_xor(v, off));
    return v;
}
__device__ __forceinline__ float leaky(float v) { return v > 0.f ? v : 0.2f * v; }

__device__ __forceinline__ void decode_edge(int e, int E0_, const int* __restrict__ ei,
                                            int& s, int& d) {
    if (e < E0_)          { s = ei[e];        d = ei[E0_ + e]; }
    else if (e < 2 * E0_) { int j = e - E0_;  s = ei[E0_ + j]; d = ei[j]; }
    else                  { s = e - 2 * E0_;  d = s; }
}

// block-wide exclusive scan over 256 threads (4 waves); wsum must hold >=4 ints
__device__ __forceinline__ int block_excl_scan_256(int v, int tid, int* wsum) {
    const int lane = tid & 63, w = tid >> 6;
    int incl = v;
    #pragma unroll
    for (int off = 1; off < 64; off <<= 1) {
        int t = __shfl_up(incl, off);
        if (lane >= off) incl += t;
    }
    if (lane == 63) wsum[w] = incl;
    __syncthreads();
    int woff = 0;
    #pragma unroll
    for (int i = 0; i < 3; ++i) if (i < w) woff += wsum[i];
    return woff + incl - v;
}

// ---------------- K1: proj(fp16) = x @ W1 ; alpha_src/alpha_dst per node (f32) -------
__global__ __launch_bounds__(256) void k_proj(
    const float* __restrict__ x, const float* __restrict__ W1,
    const float* __restrict__ a_src, const float* __restrict__ a_dst,
    __half* __restrict__ proj, float* __restrict__ asrc, float* __restrict__ adst, int N)
{
    __shared__ float4 xs[64 * 33];
    const int tid = threadIdx.x;
    const int node0 = blockIdx.x * 64;

    for (int i = tid; i < 64 * 32; i += 256) {
        int r = i >> 5, c = i & 31;
        float4 v = {0.f, 0.f, 0.f, 0.f};
        int n = node0 + r;
        if (n < N) v = *(const float4*)(x + (size_t)n * HD + c * 4);
        xs[r * 33 + c] = v;
    }
    __syncthreads();

    const int ng = tid >> 4;
    const int cg = tid & 15;
    const int c0 = cg * 8;

    float acc[4][8];
    #pragma unroll
    for (int r = 0; r < 4; ++r)
        #pragma unroll
        for (int j = 0; j < 8; ++j) acc[r][j] = 0.f;

    for (int k4 = 0; k4 < 32; ++k4) {
        float4 xv[4];
        #pragma unroll
        for (int r = 0; r < 4; ++r) xv[r] = xs[(ng * 4 + r) * 33 + k4];
        #pragma unroll
        for (int kk = 0; kk < 4; ++kk) {
            const int k = k4 * 4 + kk;
            const float4 w0 = *(const float4*)(W1 + k * HD + c0);
            const float4 w1 = *(const float4*)(W1 + k * HD + c0 + 4);
            #pragma unroll
            for (int r = 0; r < 4; ++r) {
                const float xvk = (kk == 0) ? xv[r].x : (kk == 1) ? xv[r].y : (kk == 2) ? xv[r].z : xv[r].w;
                acc[r][0] += xvk * w0.x; acc[r][1] += xvk * w0.y;
                acc[r][2] += xvk * w0.z; acc[r][3] += xvk * w0.w;
                acc[r][4] += xvk * w1.x; acc[r][5] += xvk * w1.y;
                acc[r][6] += xvk * w1.z; acc[r][7] += xvk * w1.w;
            }
        }
    }

    float as_[8], ad_[8];
    #pragma unroll
    for (int j = 0; j < 8; ++j) { as_[j] = a_src[c0 + j]; ad_[j] = a_dst[c0 + j]; }

    #pragma unroll
    for (int r = 0; r < 4; ++r) {
        const int n = node0 + ng * 4 + r;
        if (n >= N) break;
        __half2 h01 = __floats2half2_rn(acc[r][0], acc[r][1]);
        __half2 h23 = __floats2half2_rn(acc[r][2], acc[r][3]);
        __half2 h45 = __floats2half2_rn(acc[r][4], acc[r][5]);
        __half2 h67 = __floats2half2_rn(acc[r][6], acc[r][7]);
        uint4 pk;
        pk.x = *(unsigned int*)&h01; pk.y = *(unsigned int*)&h23;
        pk.z = *(unsigned int*)&h45; pk.w = *(unsigned int*)&h67;
        *(uint4*)(proj + (size_t)n * HD + c0) = pk;   // 16B aligned (c0 mult of 8)
        float ps = 0.f, pd = 0.f;
        #pragma unroll
        for (int j = 0; j < 8; ++j) { ps += acc[r][j] * as_[j]; pd += acc[r][j] * ad_[j]; }
        ps += __shfl_xor(ps, 1); ps += __shfl_xor(ps, 2);
        pd += __shfl_xor(pd, 1); pd += __shfl_xor(pd, 2);
        if ((cg & 3) == 0) {
            asrc[(size_t)n * NH + (cg >> 2)] = ps;
            adst[(size_t)n * NH + (cg >> 2)] = pd;
        }
    }
}

// ---------------- K2: degree histogram over augmented dst ----------------
__global__ void k_degree(const int* __restrict__ ei, int* __restrict__ deg, int N, int E0_) {
    const int e = blockIdx.x * blockDim.x + threadIdx.x;
    const int ea = 2 * E0_ + N;
    if (e >= ea) return;
    int s, d;
    decode_edge(e, E0_, ei, s, d);
    atomicAdd(deg + d, 1);
}

// ---------------- K3a: per-block (=per-bucket, 256 nodes) sums of deg ----------------
__global__ __launch_bounds__(256) void k_bsum(
    const int* __restrict__ deg, int* __restrict__ bsum, int N)
{
    __shared__ int wsum[4];
    const int tid = threadIdx.x;
    const int gid = blockIdx.x * 256 + tid;
    int v = (gid < N) ? deg[gid] : 0;
    int s = v;
    #pragma unroll
    for (int off = 1; off < 64; off <<= 1) s += __shfl_xor(s, off);
    if ((tid & 63) == 0) wsum[tid >> 6] = s;
    __syncthreads();
    if (tid == 0) bsum[blockIdx.x] = wsum[0] + wsum[1] + wsum[2] + wsum[3];
}

// ---------------- K3b: exclusive scan of bucket sums (NB < 256) ----------------
__global__ __launch_bounds__(256) void k_bscan(
    const int* __restrict__ bsum, int* __restrict__ boff, int* __restrict__ bcur,
    int* __restrict__ row_start, int NB, int N)
{
    __shared__ int wsum[4];
    const int tid = threadIdx.x;
    const int v = (tid < NB) ? bsum[tid] : 0;
    const int excl = block_excl_scan_256(v, tid, wsum);
    if (tid < NB) { boff[tid] = excl; bcur[tid] = excl; }
    if (tid == NB) boff[NB] = excl;            // total (v==0 past NB)
    if (tid == 255) row_start[N] = excl + v;   // grand total
}

// ---------------- K3c: per-bucket exclusive scan + offset -> row_start ----------------
__global__ __launch_bounds__(256) void k_scan2(
    const int* __restrict__ deg, const int* __restrict__ boff,
    int* __restrict__ row_start, int N)
{
    __shared__ int wsum[4];
    const int tid = threadIdx.x;
    const int gid = blockIdx.x * 256 + tid;
    const int v = (gid < N) ? deg[gid] : 0;
    const int excl = block_excl_scan_256(v, tid, wsum) + boff[blockIdx.x];
    if (gid < N) row_start[gid] = excl;
}

// ---------------- K4a: bucket-binning scatter (block-privatized reservations) ----------
__global__ __launch_bounds__(256) void k_scatter1(
    const int* __restrict__ ei, int* __restrict__ bcur, int2* __restrict__ pair,
    int N, int E0_, int NB)
{
    __shared__ int h[256];
    __shared__ int base[256];
    const int tid = threadIdx.x;
    const int ea = 2 * E0_ + N;
    const int e0 = blockIdx.x * SC_CHUNK;
    const int e1 = min(e0 + SC_CHUNK, ea);

    h[tid] = 0;
    __syncthreads();
    for (int e = e0 + tid; e < e1; e += 256) {
        int s, d; decode_edge(e, E0_, ei, s, d);
        atomicAdd(&h[d >> 8], 1);
    }
    __syncthreads();
    if (tid < NB && h[tid] > 0) base[tid] = atomicAdd(&bcur[tid], h[tid]);
    __syncthreads();
    h[tid] = 0;
    __syncthreads();
    for (int e = e0 + tid; e < e1; e += 256) {
        int s, d; decode_edge(e, E0_, ei, s, d);
        const int b = d >> 8;
        const int r = atomicAdd(&h[b], 1);
        pair[base[b] + r] = make_int2(s, d);
    }
}

// ---------------- K4b: within-bucket placement via LDS cursors ----------------
__global__ __launch_bounds__(256) void k_place(
    const int2* __restrict__ pair, const int* __restrict__ boff,
    const int* __restrict__ row_start, int* __restrict__ csr_src, int N)
{
    __shared__ int c[256];
    const int tid = threadIdx.x;
    const int b = blockIdx.x;
    const int node = b * 256 + tid;
    c[tid] = (node < N) ? row_start[node] : 0;
    __syncthreads();
    const int lo = boff[b], hi = boff[b + 1];
    for (int i = lo + tid; i < hi; i += 256) {
        const int2 p = pair[i];
        const int pos = atomicAdd(&c[p.y & 255], 1);
        csr_src[pos] = p.x;
    }
}

// ---------------- K5: softmax + aggregation (fp16 proj gather) + ELU + Wf dot --------
__global__ __launch_bounds__(256) void k_agg(
    const __half* __restrict__ proj, const int* __restrict__ row_start,
    const int* __restrict__ csr_src,
    const float* __restrict__ asrc, const float* __restrict__ adst,
    const float* __restrict__ b1, const float* __restrict__ Wf, const float* __restrict__ bf,
    float* __restrict__ out, int N)
{
    __shared__ float4 lw[4][64];   // per-wave normalized weights
    __shared__ int    ls[4][64];   // per-wave src ids
    const int wid  = threadIdx.x >> 6;
    const int lane = threadIdx.x & 63;
    const int n = blockIdx.x * 4 + wid;
    if (n >= N) return;
    const int start = row_start[n], end = row_start[n + 1];
    const int deg = end - start;
    const float4 ad4 = *(const float4*)(adst + (size_t)n * NH);
    const int hl = lane >> 4;
    const int i0 = lane * 2;

    float acc0 = 0.f, acc1 = 0.f;

    if (deg <= 64) {
        const bool live = lane < deg;
        int sl = 0;
        if (live) sl = csr_src[start + lane];
        float4 sc = {-INFINITY, -INFINITY, -INFINITY, -INFINITY};
        if (live) {
            const float4 as4 = *(const float4*)(asrc + (size_t)sl * NH);
            sc.x = leaky(as4.x + ad4.x); sc.y = leaky(as4.y + ad4.y);
            sc.z = leaky(as4.z + ad4.z); sc.w = leaky(as4.w + ad4.w);
        }
        const float m0 = wave_max(sc.x), m1 = wave_max(sc.y);
        const float m2 = wave_max(sc.z), m3 = wave_max(sc.w);
        float4 ex = {0.f, 0.f, 0.f, 0.f};
        if (live) {
            ex.x = expf(sc.x - m0); ex.y = expf(sc.y - m1);
            ex.z = expf(sc.z - m2); ex.w = expf(sc.w - m3);
        }
        const float rd0 = 1.f / fmaxf(wave_sum(ex.x), 1e-12f);
        const float rd1 = 1.f / fmaxf(wave_sum(ex.y), 1e-12f);
        const float rd2 = 1.f / fmaxf(wave_sum(ex.z), 1e-12f);
        const float rd3 = 1.f / fmaxf(wave_sum(ex.w), 1e-12f);
        lw[wid][lane] = make_float4(ex.x * rd0, ex.y * rd1, ex.z * rd2, ex.w * rd3);
        ls[wid][lane] = sl;
        asm volatile("s_waitcnt lgkmcnt(0)" ::: "memory");   // cross-lane LDS handoff, same wave
        #pragma unroll 4
        for (int k = 0; k < deg; ++k) {
            const int s = ls[wid][k];
            const float wgt = ((const float*)&lw[wid][k])[hl];
            const float2 p = __half22float2(*(const __half2*)(proj + (size_t)s * HD + i0));
            acc0 += p.x * wgt; acc1 += p.y * wgt;
        }
    } else {
        float m0 = -INFINITY, m1 = -INFINITY, m2 = -INFINITY, m3 = -INFINITY;
        for (int e = start + lane; e < end; e += 64) {
            const int s = csr_src[e];
            const float4 as4 = *(const float4*)(asrc + (size_t)s * NH);
            m0 = fmaxf(m0, leaky(as4.x + ad4.x)); m1 = fmaxf(m1, leaky(as4.y + ad4.y));
            m2 = fmaxf(m2, leaky(as4.z + ad4.z)); m3 = fmaxf(m3, leaky(as4.w + ad4.w));
        }
        m0 = wave_max(m0); m1 = wave_max(m1); m2 = wave_max(m2); m3 = wave_max(m3);
        float dn0 = 0.f, dn1 = 0.f, dn2 = 0.f, dn3 = 0.f;
        for (int e = start + lane; e < end; e += 64) {
            const int s = csr_src[e];
            const float4 as4 = *(const float4*)(asrc + (size_t)s * NH);
            dn0 += expf(leaky(as4.x + ad4.x) - m0);
            dn1 += expf(leaky(as4.y + ad4.y) - m1);
            dn2 += expf(leaky(as4.z + ad4.z) - m2);
            dn3 += expf(leaky(as4.w + ad4.w) - m3);
        }
        const float rd0 = 1.f / fmaxf(wave_sum(dn0), 1e-12f);
        const float rd1 = 1.f / fmaxf(wave_sum(dn1), 1e-12f);
        const float rd2 = 1.f / fmaxf(wave_sum(dn2), 1e-12f);
        const float rd3 = 1.f / fmaxf(wave_sum(dn3), 1e-12f);
        for (int base = start; base < end; base += 64) {
            const int cnt = min(64, end - base);
            int sl = 0; float4 w4 = {0.f, 0.f, 0.f, 0.f};
            if (lane < cnt) {
                sl = csr_src[base + lane];
                const float4 as4 = *(const float4*)(asrc + (size_t)sl * NH);
                w4.x = expf(leaky(as4.x + ad4.x) - m0) * rd0;
                w4.y = expf(leaky(as4.y + ad4.y) - m1) * rd1;
                w4.z = expf(leaky(as4.z + ad4.z) - m2) * rd2;
                w4.w = expf(leaky(as4.w + ad4.w) - m3) * rd3;
            }
            lw[wid][lane] = w4;
            ls[wid][lane] = sl;
            asm volatile("s_waitcnt lgkmcnt(0)" ::: "memory");
            #pragma unroll 4
            for (int k = 0; k < cnt; ++k) {
                const int s = ls[wid][k];
                const float wgt = ((const float*)&lw[wid][k])[hl];
                const float2 p = __half22float2(*(const __half2*)(proj + (size_t)s * HD + i0));
                acc0 += p.x * wgt; acc1 += p.y * wgt;
            }
        }
    }

    float v0 = acc0 + b1[i0], v1 = acc1 + b1[i0 + 1];
    v0 = v0 > 0.f ? v0 : expm1f(v0);
    v1 = v1 > 0.f ? v1 : expm1f(v1);
    float r = v0 * Wf[i0] + v1 * Wf[i0 + 1];
    r = wave_sum(r);
    if (lane == 0) out[n] = r + bf[0];
}

extern "C" void kernel_launch(void* const* d_in, const int* in_sizes, int n_in,
                              void* d_out, int out_size, void* d_ws, size_t ws_size,
                              hipStream_t stream) {
    const float* x     = (const float*)d_in[0];
    const int*   ei    = (const int*)d_in[1];
    const float* W1    = (const float*)d_in[2];
    const float* a_src = (const float*)d_in[3];
    const float* a_dst = (const float*)d_in[4];
    const float* b1    = (const float*)d_in[5];
    const float* Wf    = (const float*)d_in[6];
    const float* bf    = (const float*)d_in[7];
    float* out = (float*)d_out;

    const int N   = in_sizes[0] / HD;     // 50000
    const int E0_ = in_sizes[1] / 2;      // 600000
    const int EA_ = 2 * E0_ + N;          // 1,250,000
    const int NB  = (N + 255) / 256;      // 196 buckets (256 nodes each); NB < 256

    char* w = (char*)d_ws;
    auto alloc = [&](size_t bytes) { char* p = w; w += (bytes + 255) & ~(size_t)255; return p; };
    __half* proj      = (__half*)alloc((size_t)N * HD * 2);   // 12.8 MB (fp16)
    float*  asrc      = (float*)alloc((size_t)N * NH * 4);
    float*  adst      = (float*)alloc((size_t)N * NH * 4);
    int*    deg       = (int*)alloc((size_t)N * 4);
    int*    row_start = (int*)alloc((size_t)(N + 1) * 4);
    int*    csr_src   = (int*)alloc((size_t)EA_ * 4);          // 5 MB
    int2*   pair      = (int2*)alloc((size_t)EA_ * 8);         // 10 MB
    int*    bsum      = (int*)alloc((size_t)NB * 4);
    int*    boff      = (int*)alloc((size_t)(NB + 1) * 4);
    int*    bcur      = (int*)alloc((size_t)NB * 4);

    hipMemsetAsync(deg, 0, (size_t)N * 4, stream);

    k_proj<<<(N + 63) / 64, 256, 0, stream>>>(x, W1, a_src, a_dst, proj, asrc, adst, N);
    k_degree<<<(EA_ + 255) / 256, 256, 0, stream>>>(ei, deg, N, E0_);
    k_bsum<<<NB, 256, 0, stream>>>(deg, bsum, N);
    k_bscan<<<1, 256, 0, stream>>>(bsum, boff, bcur, row_start, NB, N);
    k_scan2<<<NB, 256, 0, stream>>>(deg, boff, row_start, N);
    k_scatter1<<<(EA_ + SC_CHUNK - 1) / SC_CHUNK, 256, 0, stream>>>(ei, bcur, pair, N, E0_, NB);
    k_place<<<NB, 256, 0, stream>>>(pair, boff, row_start, csr_src, N);
    k_agg<<<(N + 3) / 4, 256, 0, stream>>>(proj, row_start, csr_src, asrc, adst, b1, Wf, bf, out, N);
}

// Round 9
// 265.247 us; speedup vs baseline: 1.8587x; 1.0186x over previous
//
#include <hip/hip_runtime.h>
#include <hip/hip_fp16.h>
#include <math.h>

#define HD 128   // HEADS*OUT_DIM
#define NH 4     // HEADS
#define SC_CHUNK 4096   // edges per k_scatter1 block

typedef _Float16 f16x8 __attribute__((ext_vector_type(8)));
typedef float f32x4 __attribute__((ext_vector_type(4)));

__device__ __forceinline__ float wave_sum(float v) {
    #pragma unroll
    for (int off = 1; off < 64; off <<= 1) v += __shfl_xor(v, off);
    return v;
}
__device__ __forceinline__ float wave_max(float v) {
    #pragma unroll
    for (int off = 1; off < 64; off <<= 1) v = fmaxf(v, __shfl_xor(v, off));
    return v;
}
__device__ __forceinline__ float leaky(float v) { return v > 0.f ? v : 0.2f * v; }

__device__ __forceinline__ void decode_edge(int e, int E0_, const int* __restrict__ ei,
                                            int& s, int& d) {
    if (e < E0_)          { s = ei[e];        d = ei[E0_ + e]; }
    else if (e < 2 * E0_) { int j = e - E0_;  s = ei[E0_ + j]; d = ei[j]; }
    else                  { s = e - 2 * E0_;  d = s; }
}

// block-wide exclusive scan over 256 threads (4 waves); wsum must hold >=4 ints
__device__ __forceinline__ int block_excl_scan_256(int v, int tid, int* wsum) {
    const int lane = tid & 63, w = tid >> 6;
    int incl = v;
    #pragma unroll
    for (int off = 1; off < 64; off <<= 1) {
        int t = __shfl_up(incl, off);
        if (lane >= off) incl += t;
    }
    if (lane == 63) wsum[w] = incl;
    __syncthreads();
    int woff = 0;
    #pragma unroll
    for (int i = 0; i < 3; ++i) if (i < w) woff += wsum[i];
    return woff + incl - v;
}

// ---------------- K0: W1 (f32 [k][c]) -> w1t (fp16 [c][k]) once ----------------
__global__ __launch_bounds__(256) void k_prew(const float* __restrict__ W1,
                                              __half* __restrict__ w1t) {
    const int idx = blockIdx.x * 256 + threadIdx.x;   // 4096 = 128k x 32c4
    const int k = idx >> 5, c4 = idx & 31;
    const float4 v = *(const float4*)(W1 + k * HD + c4 * 4);
    w1t[(c4 * 4 + 0) * HD + k] = (__half)v.x;
    w1t[(c4 * 4 + 1) * HD + k] = (__half)v.y;
    w1t[(c4 * 4 + 2) * HD + k] = (__half)v.z;
    w1t[(c4 * 4 + 3) * HD + k] = (__half)v.w;
}

// ---------------- K1: proj(fp16) = x @ W1 via MFMA; alphas from f32 acc -------
// 64 nodes/block, 4 waves; wave = one 16-row M-tile x 8 N-tiles, K=128 in 4 steps.
__global__ __launch_bounds__(256) void k_proj(
    const float* __restrict__ x, const __half* __restrict__ w1t,
    const float* __restrict__ a_src, const float* __restrict__ a_dst,
    __half* __restrict__ proj, float* __restrict__ asrc, float* __restrict__ adst, int N)
{
    __shared__ __align__(16) __half xs[64 * 128];    // 16 KB, swizzled
    __shared__ __align__(16) __half wt[128 * 128];   // 32 KB, swizzled [c][k]
    const int tid = threadIdx.x;
    const int node0 = blockIdx.x * 64;

    // stage x -> fp16 LDS (zero-fill past N), swizzle halfidx ^= (row&7)<<3
    for (int i = tid; i < 64 * 32; i += 256) {
        const int r = i >> 5, c4 = i & 31;
        const int n = node0 + r;
        float4 v = {0.f, 0.f, 0.f, 0.f};
        if (n < N) v = *(const float4*)(x + (size_t)n * HD + c4 * 4);
        __half2 h01 = __floats2half2_rn(v.x, v.y);
        __half2 h23 = __floats2half2_rn(v.z, v.w);
        uint2 u; u.x = *(unsigned*)&h01; u.y = *(unsigned*)&h23;
        const int hidx = (r * 128 + c4 * 4) ^ ((r & 7) << 3);
        *(uint2*)&xs[hidx] = u;
    }
    // stage w1t -> LDS with same swizzle (16B chunks)
    {
        const int cr = tid >> 1, ha = tid & 1;
        #pragma unroll
        for (int i = 0; i < 8; ++i) {
            const int k0 = ha * 64 + i * 8;
            const int hidx = (cr * 128 + k0) ^ ((cr & 7) << 3);
            *(uint4*)&wt[hidx] = *(const uint4*)(w1t + cr * 128 + k0);
        }
    }
    __syncthreads();

    const int wid = tid >> 6, l = tid & 63;
    const int lr = l & 15, kq = l >> 4;   // A row / C col = lr; k-quarter = kq

    f32x4 acc[8];
    #pragma unroll
    for (int nt = 0; nt < 8; ++nt) acc[nt] = {0.f, 0.f, 0.f, 0.f};

    #pragma unroll
    for (int kk = 0; kk < 4; ++kk) {
        const int arow = wid * 16 + lr;
        const int ai = (arow * 128 + kk * 32 + kq * 8) ^ ((arow & 7) << 3);
        const f16x8 af = *(const f16x8*)&xs[ai];
        #pragma unroll
        for (int nt = 0; nt < 8; ++nt) {
            const int cr = nt * 16 + lr;
            const int bi = (cr * 128 + kk * 32 + kq * 8) ^ ((cr & 7) << 3);
            const f16x8 bf = *(const f16x8*)&wt[bi];
            acc[nt] = __builtin_amdgcn_mfma_f32_16x16x32_f16(af, bf, acc[nt], 0, 0, 0);
        }
    }

    float asv[8], adv[8];
    #pragma unroll
    for (int nt = 0; nt < 8; ++nt) {
        asv[nt] = a_src[nt * 16 + lr];
        adv[nt] = a_dst[nt * 16 + lr];
    }

    #pragma unroll
    for (int reg = 0; reg < 4; ++reg) {
        const int node = node0 + wid * 16 + kq * 4 + reg;   // C/D row mapping
        if (node < N) {
            #pragma unroll
            for (int nt = 0; nt < 8; ++nt)
                proj[(size_t)node * HD + nt * 16 + lr] = (__half)acc[nt][reg];
        }
        float hs[4], hd_[4];
        #pragma unroll
        for (int hh = 0; hh < 4; ++hh) {
            hs[hh]  = acc[2*hh][reg] * asv[2*hh] + acc[2*hh+1][reg] * asv[2*hh+1];
            hd_[hh] = acc[2*hh][reg] * adv[2*hh] + acc[2*hh+1][reg] * adv[2*hh+1];
        }
        #pragma unroll
        for (int off = 1; off < 16; off <<= 1) {
            #pragma unroll
            for (int hh = 0; hh < 4; ++hh) {
                hs[hh]  += __shfl_xor(hs[hh], off);
                hd_[hh] += __shfl_xor(hd_[hh], off);
            }
        }
        if (lr == 0 && node < N) {
            #pragma unroll
            for (int hh = 0; hh < 4; ++hh) {
                asrc[(size_t)node * NH + hh] = hs[hh];
                adst[(size_t)node * NH + hh] = hd_[hh];
            }
        }
    }
}

// ---------------- K2: degree histogram over augmented dst ----------------
__global__ void k_degree(const int* __restrict__ ei, int* __restrict__ deg, int N, int E0_) {
    const int e = blockIdx.x * blockDim.x + threadIdx.x;
    const int ea = 2 * E0_ + N;
    if (e >= ea) return;
    int s, d;
    decode_edge(e, E0_, ei, s, d);
    atomicAdd(deg + d, 1);
}

// ---------------- K3a: per-bucket (256 nodes) sums of deg ----------------
__global__ __launch_bounds__(256) void k_bsum(
    const int* __restrict__ deg, int* __restrict__ bsum, int N)
{
    __shared__ int wsum[4];
    const int tid = threadIdx.x;
    const int gid = blockIdx.x * 256 + tid;
    int v = (gid < N) ? deg[gid] : 0;
    int s = v;
    #pragma unroll
    for (int off = 1; off < 64; off <<= 1) s += __shfl_xor(s, off);
    if ((tid & 63) == 0) wsum[tid >> 6] = s;
    __syncthreads();
    if (tid == 0) bsum[blockIdx.x] = wsum[0] + wsum[1] + wsum[2] + wsum[3];
}

// ---------------- K3b: exclusive scan of bucket sums (NB < 256) ----------------
__global__ __launch_bounds__(256) void k_bscan(
    const int* __restrict__ bsum, int* __restrict__ boff, int* __restrict__ bcur,
    int* __restrict__ row_start, int NB, int N)
{
    __shared__ int wsum[4];
    const int tid = threadIdx.x;
    const int v = (tid < NB) ? bsum[tid] : 0;
    const int excl = block_excl_scan_256(v, tid, wsum);
    if (tid < NB) { boff[tid] = excl; bcur[tid] = excl; }
    if (tid == NB) boff[NB] = excl;
    if (tid == 255) row_start[N] = excl + v;
}

// ---------------- K3c: per-bucket scan -> row_start + cursor ----------------
__global__ __launch_bounds__(256) void k_scan2(
    const int* __restrict__ deg, const int* __restrict__ boff,
    int* __restrict__ row_start, int* __restrict__ cursor, int N)
{
    __shared__ int wsum[4];
    const int tid = threadIdx.x;
    const int gid = blockIdx.x * 256 + tid;
    const int v = (gid < N) ? deg[gid] : 0;
    const int excl = block_excl_scan_256(v, tid, wsum) + boff[blockIdx.x];
    if (gid < N) { row_start[gid] = excl; cursor[gid] = excl; }
}

// ---------------- K4a: bucket-binning scatter, single ei pass via LDS staging -------
__global__ __launch_bounds__(256) void k_scatter1(
    const int* __restrict__ ei, int* __restrict__ bcur, int2* __restrict__ pair,
    int N, int E0_, int NB)
{
    __shared__ int2 ed[SC_CHUNK];   // 32 KB staged decoded edges
    __shared__ int h[256];
    __shared__ int base[256];
    const int tid = threadIdx.x;
    const int ea = 2 * E0_ + N;
    const int e0 = blockIdx.x * SC_CHUNK;
    const int e1 = min(e0 + SC_CHUNK, ea);

    h[tid] = 0;
    __syncthreads();
    for (int e = e0 + tid; e < e1; e += 256) {
        int s, d; decode_edge(e, E0_, ei, s, d);
        ed[e - e0] = make_int2(s, d);
        atomicAdd(&h[d >> 8], 1);
    }
    __syncthreads();
    if (tid < NB && h[tid] > 0) base[tid] = atomicAdd(&bcur[tid], h[tid]);
    __syncthreads();
    h[tid] = 0;
    __syncthreads();
    const int cnt = e1 - e0;
    for (int i = tid; i < cnt; i += 256) {
        const int2 p = ed[i];
        const int b = p.y >> 8;
        const int r = atomicAdd(&h[b], 1);
        pair[base[b] + r] = p;
    }
}

// ---------------- K4b: placement from bucket-sorted pair stream ----------------
__global__ void k_place(const int2* __restrict__ pair, int* __restrict__ cursor,
                        int* __restrict__ csr_src, int total)
{
    const int i = blockIdx.x * blockDim.x + threadIdx.x;
    if (i >= total) return;
    const int2 p = pair[i];
    const int pos = atomicAdd(cursor + p.y, 1);
    csr_src[pos] = p.x;
}

// ---------------- K5: softmax + aggregation (fp16 proj gather) + ELU + Wf dot --------
__global__ __launch_bounds__(256) void k_agg(
    const __half* __restrict__ proj, const int* __restrict__ row_start,
    const int* __restrict__ csr_src,
    const float* __restrict__ asrc, const float* __restrict__ adst,
    const float* __restrict__ b1, const float* __restrict__ Wf, const float* __restrict__ bf,
    float* __restrict__ out, int N)
{
    __shared__ float4 lw[4][64];
    __shared__ int    ls[4][64];
    const int wid  = threadIdx.x >> 6;
    const int lane = threadIdx.x & 63;
    const int n = blockIdx.x * 4 + wid;
    if (n >= N) return;
    const int start = row_start[n], end = row_start[n + 1];
    const int deg = end - start;
    const float4 ad4 = *(const float4*)(adst + (size_t)n * NH);
    const int hl = lane >> 4;
    const int i0 = lane * 2;

    float acc0 = 0.f, acc1 = 0.f;

    if (deg <= 64) {
        const bool live = lane < deg;
        int sl = 0;
        if (live) sl = csr_src[start + lane];
        float4 sc = {-INFINITY, -INFINITY, -INFINITY, -INFINITY};
        if (live) {
            const float4 as4 = *(const float4*)(asrc + (size_t)sl * NH);
            sc.x = leaky(as4.x + ad4.x); sc.y = leaky(as4.y + ad4.y);
            sc.z = leaky(as4.z + ad4.z); sc.w = leaky(as4.w + ad4.w);
        }
        const float m0 = wave_max(sc.x), m1 = wave_max(sc.y);
        const float m2 = wave_max(sc.z), m3 = wave_max(sc.w);
        float4 ex = {0.f, 0.f, 0.f, 0.f};
        if (live) {
            ex.x = expf(sc.x - m0); ex.y = expf(sc.y - m1);
            ex.z = expf(sc.z - m2); ex.w = expf(sc.w - m3);
        }
        const float rd0 = 1.f / fmaxf(wave_sum(ex.x), 1e-12f);
        const float rd1 = 1.f / fmaxf(wave_sum(ex.y), 1e-12f);
        const float rd2 = 1.f / fmaxf(wave_sum(ex.z), 1e-12f);
        const float rd3 = 1.f / fmaxf(wave_sum(ex.w), 1e-12f);
        lw[wid][lane] = make_float4(ex.x * rd0, ex.y * rd1, ex.z * rd2, ex.w * rd3);
        ls[wid][lane] = sl;
        asm volatile("s_waitcnt lgkmcnt(0)" ::: "memory");
        #pragma unroll 4
        for (int k = 0; k < deg; ++k) {
            const int s = ls[wid][k];
            const float wgt = ((const float*)&lw[wid][k])[hl];
            const float2 p = __half22float2(*(const __half2*)(proj + (size_t)s * HD + i0));
            acc0 += p.x * wgt; acc1 += p.y * wgt;
        }
    } else {
        float m0 = -INFINITY, m1 = -INFINITY, m2 = -INFINITY, m3 = -INFINITY;
        for (int e = start + lane; e < end; e += 64) {
            const int s = csr_src[e];
            const float4 as4 = *(const float4*)(asrc + (size_t)s * NH);
            m0 = fmaxf(m0, leaky(as4.x + ad4.x)); m1 = fmaxf(m1, leaky(as4.y + ad4.y));
            m2 = fmaxf(m2, leaky(as4.z + ad4.z)); m3 = fmaxf(m3, leaky(as4.w + ad4.w));
        }
        m0 = wave_max(m0); m1 = wave_max(m1); m2 = wave_max(m2); m3 = wave_max(m3);
        float dn0 = 0.f, dn1 = 0.f, dn2 = 0.f, dn3 = 0.f;
        for (int e = start + lane; e < end; e += 64) {
            const int s = csr_src[e];
            const float4 as4 = *(const float4*)(asrc + (size_t)s * NH);
            dn0 += expf(leaky(as4.x + ad4.x) - m0);
            dn1 += expf(leaky(as4.y + ad4.y) - m1);
            dn2 += expf(leaky(as4.z + ad4.z) - m2);
            dn3 += expf(leaky(as4.w + ad4.w) - m3);
        }
        const float rd0 = 1.f / fmaxf(wave_sum(dn0), 1e-12f);
        const float rd1 = 1.f / fmaxf(wave_sum(dn1), 1e-12f);
        const float rd2 = 1.f / fmaxf(wave_sum(dn2), 1e-12f);
        const float rd3 = 1.f / fmaxf(wave_sum(dn3), 1e-12f);
        for (int base = start; base < end; base += 64) {
            const int cnt = min(64, end - base);
            int sl = 0; float4 w4 = {0.f, 0.f, 0.f, 0.f};
            if (lane < cnt) {
                sl = csr_src[base + lane];
                const float4 as4 = *(const float4*)(asrc + (size_t)sl * NH);
                w4.x = expf(leaky(as4.x + ad4.x) - m0) * rd0;
                w4.y = expf(leaky(as4.y + ad4.y) - m1) * rd1;
                w4.z = expf(leaky(as4.z + ad4.z) - m2) * rd2;
                w4.w = expf(leaky(as4.w + ad4.w) - m3) * rd3;
            }
            lw[wid][lane] = w4;
            ls[wid][lane] = sl;
            asm volatile("s_waitcnt lgkmcnt(0)" ::: "memory");
            #pragma unroll 4
            for (int k = 0; k < cnt; ++k) {
                const int s = ls[wid][k];
                const float wgt = ((const float*)&lw[wid][k])[hl];
                const float2 p = __half22float2(*(const __half2*)(proj + (size_t)s * HD + i0));
                acc0 += p.x * wgt; acc1 += p.y * wgt;
            }
        }
    }

    float v0 = acc0 + b1[i0], v1 = acc1 + b1[i0 + 1];
    v0 = v0 > 0.f ? v0 : expm1f(v0);
    v1 = v1 > 0.f ? v1 : expm1f(v1);
    float r = v0 * Wf[i0] + v1 * Wf[i0 + 1];
    r = wave_sum(r);
    if (lane == 0) out[n] = r + bf[0];
}

extern "C" void kernel_launch(void* const* d_in, const int* in_sizes, int n_in,
                              void* d_out, int out_size, void* d_ws, size_t ws_size,
                              hipStream_t stream) {
    const float* x     = (const float*)d_in[0];
    const int*   ei    = (const int*)d_in[1];
    const float* W1    = (const float*)d_in[2];
    const float* a_src = (const float*)d_in[3];
    const float* a_dst = (const float*)d_in[4];
    const float* b1    = (const float*)d_in[5];
    const float* Wf    = (const float*)d_in[6];
    const float* bf    = (const float*)d_in[7];
    float* out = (float*)d_out;

    const int N   = in_sizes[0] / HD;     // 50000
    const int E0_ = in_sizes[1] / 2;      // 600000
    const int EA_ = 2 * E0_ + N;          // 1,250,000
    const int NB  = (N + 255) / 256;      // 196 buckets

    char* w = (char*)d_ws;
    auto alloc = [&](size_t bytes) { char* p = w; w += (bytes + 255) & ~(size_t)255; return p; };
    __half* proj      = (__half*)alloc((size_t)N * HD * 2);   // 12.8 MB
    __half* w1t       = (__half*)alloc((size_t)HD * HD * 2);  // 32 KB
    float*  asrc      = (float*)alloc((size_t)N * NH * 4);
    float*  adst      = (float*)alloc((size_t)N * NH * 4);
    int*    deg       = (int*)alloc((size_t)N * 4);
    int*    row_start = (int*)alloc((size_t)(N + 1) * 4);
    int*    cursor    = (int*)alloc((size_t)N * 4);
    int*    csr_src   = (int*)alloc((size_t)EA_ * 4);          // 5 MB
    int2*   pair      = (int2*)alloc((size_t)EA_ * 8);         // 10 MB
    int*    bsum      = (int*)alloc((size_t)NB * 4);
    int*    boff      = (int*)alloc((size_t)(NB + 1) * 4);
    int*    bcur      = (int*)alloc((size_t)NB * 4);

    hipMemsetAsync(deg, 0, (size_t)N * 4, stream);

    k_prew<<<16, 256, 0, stream>>>(W1, w1t);
    k_proj<<<(N + 63) / 64, 256, 0, stream>>>(x, w1t, a_src, a_dst, proj, asrc, adst, N);
    k_degree<<<(EA_ + 255) / 256, 256, 0, stream>>>(ei, deg, N, E0_);
    k_bsum<<<NB, 256, 0, stream>>>(deg, bsum, N);
    k_bscan<<<1, 256, 0, stream>>>(bsum, boff, bcur, row_start, NB, N);
    k_scan2<<<NB, 256, 0, stream>>>(deg, boff, row_start, cursor, N);
    k_scatter1<<<(EA_ + SC_CHUNK - 1) / SC_CHUNK, 256, 0, stream>>>(ei, bcur, pair, N, E0_, NB);
    k_place<<<(EA_ + 255) / 256, 256, 0, stream>>>(pair, cursor, csr_src, EA_);
    k_agg<<<(N + 3) / 4, 256, 0, stream>>>(proj, row_start, csr_src, asrc, adst, b1, Wf, bf, out, N);
}

// Round 12
// 198.443 us; speedup vs baseline: 2.4845x; 1.3366x over previous
//
#include <hip/hip_runtime.h>
#include <hip/hip_fp16.h>
#include <math.h>

#define HD 128   // HEADS*OUT_DIM
#define NH 4     // HEADS
#define SC_CHUNK 4096     // edges per k_scatter1 / k_bcount block
#define PL_CAP  8192      // staged pairs per bucket in k_place2 (64 KB LDS)

typedef _Float16 f16x8 __attribute__((ext_vector_type(8)));
typedef float f32x4 __attribute__((ext_vector_type(4)));

__device__ __forceinline__ float wave_sum(float v) {
    #pragma unroll
    for (int off = 1; off < 64; off <<= 1) v += __shfl_xor(v, off);
    return v;
}
__device__ __forceinline__ float wave_max(float v) {
    #pragma unroll
    for (int off = 1; off < 64; off <<= 1) v = fmaxf(v, __shfl_xor(v, off));
    return v;
}
__device__ __forceinline__ float leaky(float v) { return v > 0.f ? v : 0.2f * v; }

__device__ __forceinline__ void decode_edge(int e, int E0_, const int* __restrict__ ei,
                                            int& s, int& d) {
    if (e < E0_)          { s = ei[e];        d = ei[E0_ + e]; }
    else if (e < 2 * E0_) { int j = e - E0_;  s = ei[E0_ + j]; d = ei[j]; }
    else                  { s = e - 2 * E0_;  d = s; }
}

// block-wide exclusive scan over 256 threads (4 waves); wsum must hold >=4 ints
__device__ __forceinline__ int block_excl_scan_256(int v, int tid, int* wsum) {
    const int lane = tid & 63, w = tid >> 6;
    int incl = v;
    #pragma unroll
    for (int off = 1; off < 64; off <<= 1) {
        int t = __shfl_up(incl, off);
        if (lane >= off) incl += t;
    }
    if (lane == 63) wsum[w] = incl;
    __syncthreads();
    int woff = 0;
    #pragma unroll
    for (int i = 0; i < 3; ++i) if (i < w) woff += wsum[i];
    return woff + incl - v;
}

// ---------------- K0: W1 f32[k][c] -> w1t fp16[c][k]; also zero bucket_cnt ---------
__global__ __launch_bounds__(256) void k_prew(const float* __restrict__ W1,
                                              __half* __restrict__ w1t,
                                              int* __restrict__ bucket_cnt, int NB) {
    const int idx = blockIdx.x * 256 + threadIdx.x;   // 4096 = 128k x 32c4
    if (blockIdx.x == 0 && threadIdx.x < NB) bucket_cnt[threadIdx.x] = 0;
    const int k = idx >> 5, c4 = idx & 31;
    const float4 v = *(const float4*)(W1 + k * HD + c4 * 4);
    w1t[(c4 * 4 + 0) * HD + k] = (__half)v.x;
    w1t[(c4 * 4 + 1) * HD + k] = (__half)v.y;
    w1t[(c4 * 4 + 2) * HD + k] = (__half)v.z;
    w1t[(c4 * 4 + 3) * HD + k] = (__half)v.w;
}

// ---------------- K1: proj(fp16) = x @ W1 via MFMA; alphas from f32 acc -------
__global__ __launch_bounds__(256) void k_proj(
    const float* __restrict__ x, const __half* __restrict__ w1t,
    const float* __restrict__ a_src, const float* __restrict__ a_dst,
    __half* __restrict__ proj, float* __restrict__ asrc, float* __restrict__ adst, int N)
{
    __shared__ __align__(16) __half xs[64 * 128];    // 16 KB, swizzled
    __shared__ __align__(16) __half wt[128 * 128];   // 32 KB, swizzled [c][k]
    const int tid = threadIdx.x;
    const int node0 = blockIdx.x * 64;

    for (int i = tid; i < 64 * 32; i += 256) {
        const int r = i >> 5, c4 = i & 31;
        const int n = node0 + r;
        float4 v = {0.f, 0.f, 0.f, 0.f};
        if (n < N) v = *(const float4*)(x + (size_t)n * HD + c4 * 4);
        __half2 h01 = __floats2half2_rn(v.x, v.y);
        __half2 h23 = __floats2half2_rn(v.z, v.w);
        uint2 u; u.x = *(unsigned*)&h01; u.y = *(unsigned*)&h23;
        const int hidx = (r * 128 + c4 * 4) ^ ((r & 7) << 3);
        *(uint2*)&xs[hidx] = u;
    }
    {
        const int cr = tid >> 1, ha = tid & 1;
        #pragma unroll
        for (int i = 0; i < 8; ++i) {
            const int k0 = ha * 64 + i * 8;
            const int hidx = (cr * 128 + k0) ^ ((cr & 7) << 3);
            *(uint4*)&wt[hidx] = *(const uint4*)(w1t + cr * 128 + k0);
        }
    }
    __syncthreads();

    const int wid = tid >> 6, l = tid & 63;
    const int lr = l & 15, kq = l >> 4;

    f32x4 acc[8];
    #pragma unroll
    for (int nt = 0; nt < 8; ++nt) acc[nt] = {0.f, 0.f, 0.f, 0.f};

    #pragma unroll
    for (int kk = 0; kk < 4; ++kk) {
        const int arow = wid * 16 + lr;
        const int ai = (arow * 128 + kk * 32 + kq * 8) ^ ((arow & 7) << 3);
        const f16x8 af = *(const f16x8*)&xs[ai];
        #pragma unroll
        for (int nt = 0; nt < 8; ++nt) {
            const int cr = nt * 16 + lr;
            const int bi = (cr * 128 + kk * 32 + kq * 8) ^ ((cr & 7) << 3);
            const f16x8 bf = *(const f16x8*)&wt[bi];
            acc[nt] = __builtin_amdgcn_mfma_f32_16x16x32_f16(af, bf, acc[nt], 0, 0, 0);
        }
    }

    float asv[8], adv[8];
    #pragma unroll
    for (int nt = 0; nt < 8; ++nt) {
        asv[nt] = a_src[nt * 16 + lr];
        adv[nt] = a_dst[nt * 16 + lr];
    }

    #pragma unroll
    for (int reg = 0; reg < 4; ++reg) {
        const int node = node0 + wid * 16 + kq * 4 + reg;
        if (node < N) {
            #pragma unroll
            for (int nt = 0; nt < 8; ++nt)
                proj[(size_t)node * HD + nt * 16 + lr] = (__half)acc[nt][reg];
        }
        float hs[4], hd_[4];
        #pragma unroll
        for (int hh = 0; hh < 4; ++hh) {
            hs[hh]  = acc[2*hh][reg] * asv[2*hh] + acc[2*hh+1][reg] * asv[2*hh+1];
            hd_[hh] = acc[2*hh][reg] * adv[2*hh] + acc[2*hh+1][reg] * adv[2*hh+1];
        }
        #pragma unroll
        for (int off = 1; off < 16; off <<= 1) {
            #pragma unroll
            for (int hh = 0; hh < 4; ++hh) {
                hs[hh]  += __shfl_xor(hs[hh], off);
                hd_[hh] += __shfl_xor(hd_[hh], off);
            }
        }
        if (lr == 0 && node < N) {
            #pragma unroll
            for (int hh = 0; hh < 4; ++hh) {
                asrc[(size_t)node * NH + hh] = hs[hh];
                adst[(size_t)node * NH + hh] = hd_[hh];
            }
        }
    }
}

// ---------------- K2: bucket histogram (196 buckets of 256 nodes) ----------------
__global__ __launch_bounds__(256) void k_bcount(
    const int* __restrict__ ei, int* __restrict__ bucket_cnt, int N, int E0_, int NB)
{
    __shared__ int h[256];
    const int tid = threadIdx.x;
    const int ea = 2 * E0_ + N;
    const int e0 = blockIdx.x * SC_CHUNK;
    const int e1 = min(e0 + SC_CHUNK, ea);
    h[tid] = 0;
    __syncthreads();
    for (int e = e0 + tid; e < e1; e += 256) {
        int d;
        if (e < E0_)          d = ei[E0_ + e];
        else if (e < 2 * E0_) d = ei[e - E0_];
        else                  d = e - 2 * E0_;
        atomicAdd(&h[d >> 8], 1);
    }
    __syncthreads();
    if (tid < NB && h[tid] > 0) atomicAdd(&bucket_cnt[tid], h[tid]);
}

// ---------------- K3: exclusive scan of bucket counts -> boff, bcur, total --------
__global__ __launch_bounds__(256) void k_bscan(
    const int* __restrict__ bucket_cnt, int* __restrict__ boff, int* __restrict__ bcur,
    int* __restrict__ row_start, int NB, int N)
{
    __shared__ int wsum[4];
    const int tid = threadIdx.x;
    const int v = (tid < NB) ? bucket_cnt[tid] : 0;
    const int excl = block_excl_scan_256(v, tid, wsum);
    if (tid < NB) { boff[tid] = excl; bcur[tid] = excl; }
    if (tid == NB) boff[NB] = excl;
    if (tid == 255) row_start[N] = excl + v;   // grand total
}

// ---------------- K4: bucket-binning scatter (single ei pass, LDS staging) --------
__global__ __launch_bounds__(256) void k_scatter1(
    const int* __restrict__ ei, int* __restrict__ bcur, int2* __restrict__ pair,
    int N, int E0_, int NB)
{
    __shared__ int2 ed[SC_CHUNK];   // 32 KB
    __shared__ int h[256];
    __shared__ int base[256];
    const int tid = threadIdx.x;
    const int ea = 2 * E0_ + N;
    const int e0 = blockIdx.x * SC_CHUNK;
    const int e1 = min(e0 + SC_CHUNK, ea);

    h[tid] = 0;
    __syncthreads();
    for (int e = e0 + tid; e < e1; e += 256) {
        int s, d; decode_edge(e, E0_, ei, s, d);
        ed[e - e0] = make_int2(s, d);
        atomicAdd(&h[d >> 8], 1);
    }
    __syncthreads();
    if (tid < NB && h[tid] > 0) base[tid] = atomicAdd(&bcur[tid], h[tid]);
    __syncthreads();
    h[tid] = 0;
    __syncthreads();
    const int cnt = e1 - e0;
    for (int i = tid; i < cnt; i += 256) {
        const int2 p = ed[i];
        const int b = p.y >> 8;
        const int r = atomicAdd(&h[b], 1);
        pair[base[b] + r] = p;
    }
}

// ---------------- K5: per-bucket node-level counting sort in LDS ----------------
__global__ __launch_bounds__(256) void k_place2(
    const int2* __restrict__ pair, const int* __restrict__ boff,
    int* __restrict__ row_start, int* __restrict__ csr_src, int N)
{
    __shared__ int2 ed[PL_CAP];     // 64 KB
    __shared__ int cnt[256];
    __shared__ int wsum[4];
    const int tid = threadIdx.x;
    const int b = blockIdx.x;
    const int lo = boff[b], hi = boff[b + 1];
    const int sz = hi - lo;
    const int node = b * 256 + tid;

    cnt[tid] = 0;
    __syncthreads();

    if (sz <= PL_CAP) {
        for (int i = tid; i < sz; i += 256) {
            const int2 p = pair[lo + i];
            ed[i] = p;
            atomicAdd(&cnt[p.y & 255], 1);
        }
        __syncthreads();
        const int v = cnt[tid];
        const int excl = block_excl_scan_256(v, tid, wsum) + lo;
        if (node < N) row_start[node] = excl;
        __syncthreads();
        cnt[tid] = excl;   // becomes cursor
        __syncthreads();
        for (int i = tid; i < sz; i += 256) {
            const int2 p = ed[i];
            const int pos = atomicAdd(&cnt[p.y & 255], 1);
            csr_src[pos] = p.x;
        }
    } else {
        // streaming fallback (bucket larger than LDS capacity)
        for (int i = tid; i < sz; i += 256)
            atomicAdd(&cnt[pair[lo + i].y & 255], 1);
        __syncthreads();
        const int v = cnt[tid];
        const int excl = block_excl_scan_256(v, tid, wsum) + lo;
        if (node < N) row_start[node] = excl;
        __syncthreads();
        cnt[tid] = excl;
        __syncthreads();
        for (int i = tid; i < sz; i += 256) {
            const int2 p = pair[lo + i];
            const int pos = atomicAdd(&cnt[p.y & 255], 1);
            csr_src[pos] = p.x;
        }
    }
}

// ---------------- K6: softmax + aggregation (fp16 proj gather) + ELU + Wf dot --------
__global__ __launch_bounds__(256) void k_agg(
    const __half* __restrict__ proj, const int* __restrict__ row_start,
    const int* __restrict__ csr_src,
    const float* __restrict__ asrc, const float* __restrict__ adst,
    const float* __restrict__ b1, const float* __restrict__ Wf, const float* __restrict__ bf,
    float* __restrict__ out, int N)
{
    __shared__ float4 lw[4][64];
    __shared__ int    ls[4][64];
    const int wid  = threadIdx.x >> 6;
    const int lane = threadIdx.x & 63;
    const int n = blockIdx.x * 4 + wid;
    if (n >= N) return;
    const int start = row_start[n], end = row_start[n + 1];
    const int deg = end - start;
    const float4 ad4 = *(const float4*)(adst + (size_t)n * NH);
    const int hl = lane >> 4;
    const int i0 = lane * 2;

    float acc0 = 0.f, acc1 = 0.f;

    if (deg <= 64) {
        const bool live = lane < deg;
        int sl = 0;
        if (live) sl = csr_src[start + lane];
        float4 sc = {-INFINITY, -INFINITY, -INFINITY, -INFINITY};
        if (live) {
            const float4 as4 = *(const float4*)(asrc + (size_t)sl * NH);
            sc.x = leaky(as4.x + ad4.x); sc.y = leaky(as4.y + ad4.y);
            sc.z = leaky(as4.z + ad4.z); sc.w = leaky(as4.w + ad4.w);
        }
        const float m0 = wave_max(sc.x), m1 = wave_max(sc.y);
        const float m2 = wave_max(sc.z), m3 = wave_max(sc.w);
        float4 ex = {0.f, 0.f, 0.f, 0.f};
        if (live) {
            ex.x = expf(sc.x - m0); ex.y = expf(sc.y - m1);
            ex.z = expf(sc.z - m2); ex.w = expf(sc.w - m3);
        }
        const float rd0 = 1.f / fmaxf(wave_sum(ex.x), 1e-12f);
        const float rd1 = 1.f / fmaxf(wave_sum(ex.y), 1e-12f);
        const float rd2 = 1.f / fmaxf(wave_sum(ex.z), 1e-12f);
        const float rd3 = 1.f / fmaxf(wave_sum(ex.w), 1e-12f);
        lw[wid][lane] = make_float4(ex.x * rd0, ex.y * rd1, ex.z * rd2, ex.w * rd3);
        ls[wid][lane] = sl;
        asm volatile("s_waitcnt lgkmcnt(0)" ::: "memory");
        #pragma unroll 4
        for (int k = 0; k < deg; ++k) {
            const int s = ls[wid][k];
            const float wgt = ((const float*)&lw[wid][k])[hl];
            const float2 p = __half22float2(*(const __half2*)(proj + (size_t)s * HD + i0));
            acc0 += p.x * wgt; acc1 += p.y * wgt;
        }
    } else {
        float m0 = -INFINITY, m1 = -INFINITY, m2 = -INFINITY, m3 = -INFINITY;
        for (int e = start + lane; e < end; e += 64) {
            const int s = csr_src[e];
            const float4 as4 = *(const float4*)(asrc + (size_t)s * NH);
            m0 = fmaxf(m0, leaky(as4.x + ad4.x)); m1 = fmaxf(m1, leaky(as4.y + ad4.y));
            m2 = fmaxf(m2, leaky(as4.z + ad4.z)); m3 = fmaxf(m3, leaky(as4.w + ad4.w));
        }
        m0 = wave_max(m0); m1 = wave_max(m1); m2 = wave_max(m2); m3 = wave_max(m3);
        float dn0 = 0.f, dn1 = 0.f, dn2 = 0.f, dn3 = 0.f;
        for (int e = start + lane; e < end; e += 64) {
            const int s = csr_src[e];
            const float4 as4 = *(const float4*)(asrc + (size_t)s * NH);
            dn0 += expf(leaky(as4.x + ad4.x) - m0);
            dn1 += expf(leaky(as4.y + ad4.y) - m1);
            dn2 += expf(leaky(as4.z + ad4.z) - m2);
            dn3 += expf(leaky(as4.w + ad4.w) - m3);
        }
        const float rd0 = 1.f / fmaxf(wave_sum(dn0), 1e-12f);
        const float rd1 = 1.f / fmaxf(wave_sum(dn1), 1e-12f);
        const float rd2 = 1.f / fmaxf(wave_sum(dn2), 1e-12f);
        const float rd3 = 1.f / fmaxf(wave_sum(dn3), 1e-12f);
        for (int base = start; base < end; base += 64) {
            const int cnt = min(64, end - base);
            int sl = 0; float4 w4 = {0.f, 0.f, 0.f, 0.f};
            if (lane < cnt) {
                sl = csr_src[base + lane];
                const float4 as4 = *(const float4*)(asrc + (size_t)sl * NH);
                w4.x = expf(leaky(as4.x + ad4.x) - m0) * rd0;
                w4.y = expf(leaky(as4.y + ad4.y) - m1) * rd1;
                w4.z = expf(leaky(as4.z + ad4.z) - m2) * rd2;
                w4.w = expf(leaky(as4.w + ad4.w) - m3) * rd3;
            }
            lw[wid][lane] = w4;
            ls[wid][lane] = sl;
            asm volatile("s_waitcnt lgkmcnt(0)" ::: "memory");
            #pragma unroll 4
            for (int k = 0; k < cnt; ++k) {
                const int s = ls[wid][k];
                const float wgt = ((const float*)&lw[wid][k])[hl];
                const float2 p = __half22float2(*(const __half2*)(proj + (size_t)s * HD + i0));
                acc0 += p.x * wgt; acc1 += p.y * wgt;
            }
        }
    }

    float v0 = acc0 + b1[i0], v1 = acc1 + b1[i0 + 1];
    v0 = v0 > 0.f ? v0 : expm1f(v0);
    v1 = v1 > 0.f ? v1 : expm1f(v1);
    float r = v0 * Wf[i0] + v1 * Wf[i0 + 1];
    r = wave_sum(r);
    if (lane == 0) out[n] = r + bf[0];
}

extern "C" void kernel_launch(void* const* d_in, const int* in_sizes, int n_in,
                              void* d_out, int out_size, void* d_ws, size_t ws_size,
                              hipStream_t stream) {
    const float* x     = (const float*)d_in[0];
    const int*   ei    = (const int*)d_in[1];
    const float* W1    = (const float*)d_in[2];
    const float* a_src = (const float*)d_in[3];
    const float* a_dst = (const float*)d_in[4];
    const float* b1    = (const float*)d_in[5];
    const float* Wf    = (const float*)d_in[6];
    const float* bf    = (const float*)d_in[7];
    float* out = (float*)d_out;

    const int N   = in_sizes[0] / HD;     // 50000
    const int E0_ = in_sizes[1] / 2;      // 600000
    const int EA_ = 2 * E0_ + N;          // 1,250,000
    const int NB  = (N + 255) / 256;      // 196 buckets

    char* w = (char*)d_ws;
    auto alloc = [&](size_t bytes) { char* p = w; w += (bytes + 255) & ~(size_t)255; return p; };
    __half* proj       = (__half*)alloc((size_t)N * HD * 2);   // 12.8 MB
    __half* w1t        = (__half*)alloc((size_t)HD * HD * 2);  // 32 KB
    float*  asrc       = (float*)alloc((size_t)N * NH * 4);
    float*  adst       = (float*)alloc((size_t)N * NH * 4);
    int*    row_start  = (int*)alloc((size_t)(N + 1) * 4);
    int*    csr_src    = (int*)alloc((size_t)EA_ * 4);          // 5 MB
    int2*   pair       = (int2*)alloc((size_t)EA_ * 8);         // 10 MB
    int*    bucket_cnt = (int*)alloc((size_t)NB * 4);
    int*    boff       = (int*)alloc((size_t)(NB + 1) * 4);
    int*    bcur       = (int*)alloc((size_t)NB * 4);

    k_prew<<<16, 256, 0, stream>>>(W1, w1t, bucket_cnt, NB);
    k_proj<<<(N + 63) / 64, 256, 0, stream>>>(x, w1t, a_src, a_dst, proj, asrc, adst, N);
    k_bcount<<<(EA_ + SC_CHUNK - 1) / SC_CHUNK, 256, 0, stream>>>(ei, bucket_cnt, N, E0_, NB);
    k_bscan<<<1, 256, 0, stream>>>(bucket_cnt, boff, bcur, row_start, NB, N);
    k_scatter1<<<(EA_ + SC_CHUNK - 1) / SC_CHUNK, 256, 0, stream>>>(ei, bcur, pair, N, E0_, NB);
    k_place2<<<NB, 256, 0, stream>>>(pair, boff, row_start, csr_src, N);
    k_agg<<<(N + 3) / 4, 256, 0, stream>>>(proj, row_start, csr_src, asrc, adst, b1, Wf, bf, out, N);
}

// Round 14
// 185.009 us; speedup vs baseline: 2.6649x; 1.0726x over previous
//
#include <hip/hip_runtime.h>
#include <hip/hip_fp16.h>
#include <math.h>

#define HD 128    // HEADS*OUT_DIM
#define NH 4      // HEADS
#define SC_CHUNK 4096   // edges per k_scatter0 block
#define PAIR_CAP 8192   // per-bucket slack capacity (mean 6378, sigma ~80 -> 22+ sigma)

typedef _Float16 f16x8 __attribute__((ext_vector_type(8)));
typedef float f32x4 __attribute__((ext_vector_type(4)));

__device__ __forceinline__ float wave_sum(float v) {
    #pragma unroll
    for (int off = 1; off < 64; off <<= 1) v += __shfl_xor(v, off);
    return v;
}
__device__ __forceinline__ float wave_max(float v) {
    #pragma unroll
    for (int off = 1; off < 64; off <<= 1) v = fmaxf(v, __shfl_xor(v, off));
    return v;
}
__device__ __forceinline__ float leaky(float v) { return v > 0.f ? v : 0.2f * v; }

__device__ __forceinline__ void decode_edge(int e, int E0_, const int* __restrict__ ei,
                                            int& s, int& d) {
    if (e < E0_)          { s = ei[e];        d = ei[E0_ + e]; }
    else if (e < 2 * E0_) { int j = e - E0_;  s = ei[E0_ + j]; d = ei[j]; }
    else                  { s = e - 2 * E0_;  d = s; }
}

// block-wide exclusive scan over 256 threads (4 waves); wsum must hold >=4 ints
__device__ __forceinline__ int block_excl_scan_256(int v, int tid, int* wsum) {
    const int lane = tid & 63, w = tid >> 6;
    int incl = v;
    #pragma unroll
    for (int off = 1; off < 64; off <<= 1) {
        int t = __shfl_up(incl, off);
        if (lane >= off) incl += t;
    }
    if (lane == 63) wsum[w] = incl;
    __syncthreads();
    int woff = 0;
    #pragma unroll
    for (int i = 0; i < 3; ++i) if (i < w) woff += wsum[i];
    return woff + incl - v;
}

// ---------------- K0: W1 f32[k][c] -> w1t fp16[c][k]; zero bucket_fill ---------
__global__ __launch_bounds__(256) void k_prew(const float* __restrict__ W1,
                                              __half* __restrict__ w1t,
                                              int* __restrict__ bucket_fill, int NB) {
    const int idx = blockIdx.x * 256 + threadIdx.x;   // 4096 = 128k x 32c4
    if (blockIdx.x == 0 && threadIdx.x < NB) bucket_fill[threadIdx.x] = 0;
    const int k = idx >> 5, c4 = idx & 31;
    const float4 v = *(const float4*)(W1 + k * HD + c4 * 4);
    w1t[(c4 * 4 + 0) * HD + k] = (__half)v.x;
    w1t[(c4 * 4 + 1) * HD + k] = (__half)v.y;
    w1t[(c4 * 4 + 2) * HD + k] = (__half)v.z;
    w1t[(c4 * 4 + 3) * HD + k] = (__half)v.w;
}

// ---------------- K1: proj(fp16) = x @ W1 via MFMA; alphas from f32 acc -------
__global__ __launch_bounds__(256) void k_proj(
    const float* __restrict__ x, const __half* __restrict__ w1t,
    const float* __restrict__ a_src, const float* __restrict__ a_dst,
    __half* __restrict__ proj, float* __restrict__ asrc, float* __restrict__ adst, int N)
{
    __shared__ __align__(16) __half xs[64 * 128];    // 16 KB, swizzled
    __shared__ __align__(16) __half wt[128 * 128];   // 32 KB, swizzled [c][k]
    const int tid = threadIdx.x;
    const int node0 = blockIdx.x * 64;

    for (int i = tid; i < 64 * 32; i += 256) {
        const int r = i >> 5, c4 = i & 31;
        const int n = node0 + r;
        float4 v = {0.f, 0.f, 0.f, 0.f};
        if (n < N) v = *(const float4*)(x + (size_t)n * HD + c4 * 4);
        __half2 h01 = __floats2half2_rn(v.x, v.y);
        __half2 h23 = __floats2half2_rn(v.z, v.w);
        uint2 u; u.x = *(unsigned*)&h01; u.y = *(unsigned*)&h23;
        const int hidx = (r * 128 + c4 * 4) ^ ((r & 7) << 3);
        *(uint2*)&xs[hidx] = u;
    }
    {
        const int cr = tid >> 1, ha = tid & 1;
        #pragma unroll
        for (int i = 0; i < 8; ++i) {
            const int k0 = ha * 64 + i * 8;
            const int hidx = (cr * 128 + k0) ^ ((cr & 7) << 3);
            *(uint4*)&wt[hidx] = *(const uint4*)(w1t + cr * 128 + k0);
        }
    }
    __syncthreads();

    const int wid = tid >> 6, l = tid & 63;
    const int lr = l & 15, kq = l >> 4;

    f32x4 acc[8];
    #pragma unroll
    for (int nt = 0; nt < 8; ++nt) acc[nt] = {0.f, 0.f, 0.f, 0.f};

    #pragma unroll
    for (int kk = 0; kk < 4; ++kk) {
        const int arow = wid * 16 + lr;
        const int ai = (arow * 128 + kk * 32 + kq * 8) ^ ((arow & 7) << 3);
        const f16x8 af = *(const f16x8*)&xs[ai];
        #pragma unroll
        for (int nt = 0; nt < 8; ++nt) {
            const int cr = nt * 16 + lr;
            const int bi = (cr * 128 + kk * 32 + kq * 8) ^ ((cr & 7) << 3);
            const f16x8 bf = *(const f16x8*)&wt[bi];
            acc[nt] = __builtin_amdgcn_mfma_f32_16x16x32_f16(af, bf, acc[nt], 0, 0, 0);
        }
    }

    float asv[8], adv[8];
    #pragma unroll
    for (int nt = 0; nt < 8; ++nt) {
        asv[nt] = a_src[nt * 16 + lr];
        adv[nt] = a_dst[nt * 16 + lr];
    }

    #pragma unroll
    for (int reg = 0; reg < 4; ++reg) {
        const int node = node0 + wid * 16 + kq * 4 + reg;
        if (node < N) {
            #pragma unroll
            for (int nt = 0; nt < 8; ++nt)
                proj[(size_t)node * HD + nt * 16 + lr] = (__half)acc[nt][reg];
        }
        float hs[4], hd_[4];
        #pragma unroll
        for (int hh = 0; hh < 4; ++hh) {
            hs[hh]  = acc[2*hh][reg] * asv[2*hh] + acc[2*hh+1][reg] * asv[2*hh+1];
            hd_[hh] = acc[2*hh][reg] * adv[2*hh] + acc[2*hh+1][reg] * adv[2*hh+1];
        }
        #pragma unroll
        for (int off = 1; off < 16; off <<= 1) {
            #pragma unroll
            for (int hh = 0; hh < 4; ++hh) {
                hs[hh]  += __shfl_xor(hs[hh], off);
                hd_[hh] += __shfl_xor(hd_[hh], off);
            }
        }
        if (lr == 0 && node < N) {
            #pragma unroll
            for (int hh = 0; hh < 4; ++hh) {
                asrc[(size_t)node * NH + hh] = hs[hh];
                adst[(size_t)node * NH + hh] = hd_[hh];
            }
        }
    }
}

// ---------------- K2: direct bucket scatter into over-allocated regions ----------
// LDS-privatized hist -> one global atomic per (block,bucket) -> ranked writes.
__global__ __launch_bounds__(256) void k_scatter0(
    const int* __restrict__ ei, int* __restrict__ bucket_fill, int2* __restrict__ pair,
    int N, int E0_, int NB)
{
    __shared__ int2 ed[SC_CHUNK];   // 32 KB
    __shared__ int h[256];
    __shared__ int base[256];
    const int tid = threadIdx.x;
    const int ea = 2 * E0_ + N;
    const int e0 = blockIdx.x * SC_CHUNK;
    const int e1 = min(e0 + SC_CHUNK, ea);

    h[tid] = 0;
    __syncthreads();
    for (int e = e0 + tid; e < e1; e += 256) {
        int s, d; decode_edge(e, E0_, ei, s, d);
        ed[e - e0] = make_int2(s, d);
        atomicAdd(&h[d >> 8], 1);
    }
    __syncthreads();
    if (tid < NB && h[tid] > 0) base[tid] = atomicAdd(&bucket_fill[tid], h[tid]);
    __syncthreads();
    h[tid] = 0;
    __syncthreads();
    const int cnt = e1 - e0;
    for (int i = tid; i < cnt; i += 256) {
        const int2 p = ed[i];
        const int b = p.y >> 8;
        const int r = atomicAdd(&h[b], 1);
        const int pos = base[b] + r;
        if (pos < PAIR_CAP)   // 22-sigma guard: never true statistically
            pair[(size_t)b * PAIR_CAP + pos] = p;
    }
}

// ---------------- K3: per-bucket counting sort; redundant fill-scan gives bases ----
__global__ __launch_bounds__(256) void k_place2b(
    const int2* __restrict__ pair, const int* __restrict__ bucket_fill,
    int* __restrict__ row_start, int* __restrict__ csr_src, int N, int NB)
{
    __shared__ int2 ed[PAIR_CAP];   // 64 KB
    __shared__ int cnt[256];
    __shared__ int wsum[4];
    __shared__ int sh_lo, sh_sz;
    const int tid = threadIdx.x;
    const int b = blockIdx.x;
    const int node = b * 256 + tid;

    // redundant exclusive scan over the 196 bucket fills -> this bucket's csr base
    const int f = (tid < NB) ? min(bucket_fill[tid], PAIR_CAP) : 0;
    const int ex = block_excl_scan_256(f, tid, wsum);
    if (tid == b) { sh_lo = ex; sh_sz = f; }
    if (b == 0 && tid == NB - 1) row_start[N] = ex + f;   // grand total
    __syncthreads();
    const int lo = sh_lo, sz = sh_sz;

    cnt[tid] = 0;
    __syncthreads();
    for (int i = tid; i < sz; i += 256) {
        const int2 p = pair[(size_t)b * PAIR_CAP + i];
        ed[i] = p;
        atomicAdd(&cnt[p.y & 255], 1);
    }
    __syncthreads();
    const int v = cnt[tid];
    const int excl = block_excl_scan_256(v, tid, wsum) + lo;
    if (node < N) row_start[node] = excl;
    __syncthreads();
    cnt[tid] = excl;   // becomes cursor
    __syncthreads();
    for (int i = tid; i < sz; i += 256) {
        const int2 p = ed[i];
        const int pos = atomicAdd(&cnt[p.y & 255], 1);
        csr_src[pos] = p.x;
    }
}

// ---------------- K4: softmax + aggregation (fp16 proj gather) + ELU + Wf dot --------
__global__ __launch_bounds__(256) void k_agg(
    const __half* __restrict__ proj, const int* __restrict__ row_start,
    const int* __restrict__ csr_src,
    const float* __restrict__ asrc, const float* __restrict__ adst,
    const float* __restrict__ b1, const float* __restrict__ Wf, const float* __restrict__ bf,
    float* __restrict__ out, int N)
{
    __shared__ float4 lw[4][64];
    __shared__ int    ls[4][64];
    const int wid  = threadIdx.x >> 6;
    const int lane = threadIdx.x & 63;
    const int n = blockIdx.x * 4 + wid;
    if (n >= N) return;
    const int start = row_start[n], end = row_start[n + 1];
    const int deg = end - start;
    const float4 ad4 = *(const float4*)(adst + (size_t)n * NH);
    const int hl = lane >> 4;
    const int i0 = lane * 2;

    float acc0 = 0.f, acc1 = 0.f;

    if (deg <= 64) {
        const bool live = lane < deg;
        int sl = 0;
        if (live) sl = csr_src[start + lane];
        float4 sc = {-INFINITY, -INFINITY, -INFINITY, -INFINITY};
        if (live) {
            const float4 as4 = *(const float4*)(asrc + (size_t)sl * NH);
            sc.x = leaky(as4.x + ad4.x); sc.y = leaky(as4.y + ad4.y);
            sc.z = leaky(as4.z + ad4.z); sc.w = leaky(as4.w + ad4.w);
        }
        const float m0 = wave_max(sc.x), m1 = wave_max(sc.y);
        const float m2 = wave_max(sc.z), m3 = wave_max(sc.w);
        float4 ex = {0.f, 0.f, 0.f, 0.f};
        if (live) {
            ex.x = __expf(sc.x - m0); ex.y = __expf(sc.y - m1);
            ex.z = __expf(sc.z - m2); ex.w = __expf(sc.w - m3);
        }
        const float rd0 = 1.f / fmaxf(wave_sum(ex.x), 1e-12f);
        const float rd1 = 1.f / fmaxf(wave_sum(ex.y), 1e-12f);
        const float rd2 = 1.f / fmaxf(wave_sum(ex.z), 1e-12f);
        const float rd3 = 1.f / fmaxf(wave_sum(ex.w), 1e-12f);
        lw[wid][lane] = make_float4(ex.x * rd0, ex.y * rd1, ex.z * rd2, ex.w * rd3);
        ls[wid][lane] = sl;
        asm volatile("s_waitcnt lgkmcnt(0)" ::: "memory");
        #pragma unroll 4
        for (int k = 0; k < deg; ++k) {
            const int s = ls[wid][k];
            const float wgt = ((const float*)&lw[wid][k])[hl];
            const float2 p = __half22float2(*(const __half2*)(proj + (size_t)s * HD + i0));
            acc0 += p.x * wgt; acc1 += p.y * wgt;
        }
    } else {
        float m0 = -INFINITY, m1 = -INFINITY, m2 = -INFINITY, m3 = -INFINITY;
        for (int e = start + lane; e < end; e += 64) {
            const int s = csr_src[e];
            const float4 as4 = *(const float4*)(asrc + (size_t)s * NH);
            m0 = fmaxf(m0, leaky(as4.x + ad4.x)); m1 = fmaxf(m1, leaky(as4.y + ad4.y));
            m2 = fmaxf(m2, leaky(as4.z + ad4.z)); m3 = fmaxf(m3, leaky(as4.w + ad4.w));
        }
        m0 = wave_max(m0); m1 = wave_max(m1); m2 = wave_max(m2); m3 = wave_max(m3);
        float dn0 = 0.f, dn1 = 0.f, dn2 = 0.f, dn3 = 0.f;
        for (int e = start + lane; e < end; e += 64) {
            const int s = csr_src[e];
            const float4 as4 = *(const float4*)(asrc + (size_t)s * NH);
            dn0 += __expf(leaky(as4.x + ad4.x) - m0);
            dn1 += __expf(leaky(as4.y + ad4.y) - m1);
            dn2 += __expf(leaky(as4.z + ad4.z) - m2);
            dn3 += __expf(leaky(as4.w + ad4.w) - m3);
        }
        const float rd0 = 1.f / fmaxf(wave_sum(dn0), 1e-12f);
        const float rd1 = 1.f / fmaxf(wave_sum(dn1), 1e-12f);
        const float rd2 = 1.f / fmaxf(wave_sum(dn2), 1e-12f);
        const float rd3 = 1.f / fmaxf(wave_sum(dn3), 1e-12f);
        for (int base = start; base < end; base += 64) {
            const int cnt = min(64, end - base);
            int sl = 0; float4 w4 = {0.f, 0.f, 0.f, 0.f};
            if (lane < cnt) {
                sl = csr_src[base + lane];
                const float4 as4 = *(const float4*)(asrc + (size_t)sl * NH);
                w4.x = __expf(leaky(as4.x + ad4.x) - m0) * rd0;
                w4.y = __expf(leaky(as4.y + ad4.y) - m1) * rd1;
                w4.z = __expf(leaky(as4.z + ad4.z) - m2) * rd2;
                w4.w = __expf(leaky(as4.w + ad4.w) - m3) * rd3;
            }
            lw[wid][lane] = w4;
            ls[wid][lane] = sl;
            asm volatile("s_waitcnt lgkmcnt(0)" ::: "memory");
            #pragma unroll 4
            for (int k = 0; k < cnt; ++k) {
                const int s = ls[wid][k];
                const float wgt = ((const float*)&lw[wid][k])[hl];
                const float2 p = __half22float2(*(const __half2*)(proj + (size_t)s * HD + i0));
                acc0 += p.x * wgt; acc1 += p.y * wgt;
            }
        }
    }

    float v0 = acc0 + b1[i0], v1 = acc1 + b1[i0 + 1];
    v0 = v0 > 0.f ? v0 : expm1f(v0);
    v1 = v1 > 0.f ? v1 : expm1f(v1);
    float r = v0 * Wf[i0] + v1 * Wf[i0 + 1];
    r = wave_sum(r);
    if (lane == 0) out[n] = r + bf[0];
}

extern "C" void kernel_launch(void* const* d_in, const int* in_sizes, int n_in,
                              void* d_out, int out_size, void* d_ws, size_t ws_size,
                              hipStream_t stream) {
    const float* x     = (const float*)d_in[0];
    const int*   ei    = (const int*)d_in[1];
    const float* W1    = (const float*)d_in[2];
    const float* a_src = (const float*)d_in[3];
    const float* a_dst = (const float*)d_in[4];
    const float* b1    = (const float*)d_in[5];
    const float* Wf    = (const float*)d_in[6];
    const float* bf    = (const float*)d_in[7];
    float* out = (float*)d_out;

    const int N   = in_sizes[0] / HD;     // 50000
    const int E0_ = in_sizes[1] / 2;      // 600000
    const int EA_ = 2 * E0_ + N;          // 1,250,000
    const int NB  = (N + 255) / 256;      // 196 buckets

    char* w = (char*)d_ws;
    auto alloc = [&](size_t bytes) { char* p = w; w += (bytes + 255) & ~(size_t)255; return p; };
    __half* proj        = (__half*)alloc((size_t)N * HD * 2);       // 12.8 MB
    __half* w1t         = (__half*)alloc((size_t)HD * HD * 2);      // 32 KB
    float*  asrc        = (float*)alloc((size_t)N * NH * 4);
    float*  adst        = (float*)alloc((size_t)N * NH * 4);
    int*    row_start   = (int*)alloc((size_t)(N + 1) * 4);
    int*    csr_src     = (int*)alloc((size_t)EA_ * 4);             // 5 MB
    int2*   pair        = (int2*)alloc((size_t)NB * PAIR_CAP * 8);  // 12.8 MB
    int*    bucket_fill = (int*)alloc((size_t)NB * 4);

    k_prew<<<16, 256, 0, stream>>>(W1, w1t, bucket_fill, NB);
    k_proj<<<(N + 63) / 64, 256, 0, stream>>>(x, w1t, a_src, a_dst, proj, asrc, adst, N);
    k_scatter0<<<(EA_ + SC_CHUNK - 1) / SC_CHUNK, 256, 0, stream>>>(ei, bucket_fill, pair, N, E0_, NB);
    k_place2b<<<NB, 256, 0, stream>>>(pair, bucket_fill, row_start, csr_src, N, NB);
    k_agg<<<(N + 3) / 4, 256, 0, stream>>>(proj, row_start, csr_src, asrc, adst, b1, Wf, bf, out, N);
}